// Round 7
// baseline (819.294 us; speedup 1.0000x reference)
//
#include <hip/hip_runtime.h>
#include <cstdint>

#define K_SEL 4768
#define W75 75
#define CAND_CAP 16384
#define NBIN 4096
#define SPEC 16

struct P5 { const float* p[5]; };

__device__ __forceinline__ unsigned fsortkey(float f) {
  unsigned b = __float_as_uint(f);
  return (b & 0x80000000u) ? ~b : (b | 0x80000000u);
}

// ------- histogram of sortable-logit top-12 bits per (img,lvl): per-block partials ------
__global__ __launch_bounds__(256) void k_hist(P5 obj, unsigned* phist) {
  int p = blockIdx.y; int img = p / 5, lvl = p % 5;
  int f = 256 >> lvl; int n = 3 * f * f;
  __shared__ unsigned lh[NBIN];
  for (int b = threadIdx.x; b < NBIN; b += 256) lh[b] = 0;
  __syncthreads();
  int chunk = (n + gridDim.x - 1) / gridDim.x;
  int e0 = blockIdx.x * chunk, e1 = min(n, e0 + chunk);
  const float* src = obj.p[lvl] + (size_t)img * n;
  for (int e = e0 + threadIdx.x; e < e1; e += 256) {
    unsigned sv = fsortkey(src[e]);
    atomicAdd(&lh[sv >> 20], 1u);
  }
  __syncthreads();
  unsigned* dst = phist + ((size_t)(p * 8 + blockIdx.x)) * NBIN;
  for (int b = threadIdx.x; b < NBIN; b += 256) dst[b] = lh[b];   // unconditional: no pre-zero
}

// ------- sum partials, find threshold bin B (count(bin >= B) >= kk), zero cnt ----------
__global__ __launch_bounds__(256) void k_thresh(const unsigned* phist, int* Bthr, unsigned* cnt) {
  int p = blockIdx.x; int lvl = p % 5;
  unsigned kk = (lvl == 4) ? 768u : 1000u;
  __shared__ unsigned hsum[NBIN];
  __shared__ unsigned csum[256];
  int c = threadIdx.x;
  unsigned tot[16];
#pragma unroll
  for (int k = 0; k < 16; ++k) tot[k] = 0;
  for (int g = 0; g < 8; ++g) {
    const unsigned* hp = phist + ((size_t)(p * 8 + g)) * NBIN + c * 16;
#pragma unroll
    for (int k = 0; k < 16; ++k) tot[k] += hp[k];
  }
  unsigned s = 0;
#pragma unroll
  for (int k = 0; k < 16; ++k) { hsum[c * 16 + k] = tot[k]; s += tot[k]; }
  csum[c] = s;
  __syncthreads();
  if (c == 0) {
    unsigned acc = 0; int B = 0;
    for (int cc = 255; cc >= 0; --cc) {
      if (acc + csum[cc] >= kk) {
        for (int b = 15; b >= 0; --b) {
          acc += hsum[cc * 16 + b];
          if (acc >= kk) { B = cc * 16 + b; break; }
        }
        break;
      }
      acc += csum[cc];
    }
    Bthr[p] = B;
    cnt[p] = 0;                              // replaces ws memset for gather's counter
  }
}

// ------- gather candidates (bin >= B), wave-aggregated atomics, grid-stride ------------
__global__ __launch_bounds__(256) void k_gather(P5 obj, const int* Bthr, unsigned* cnt,
                                                unsigned long long* ck) {
  int p = blockIdx.y; int img = p / 5, lvl = p % 5;
  int f = 256 >> lvl; int hw = f * f; int n = 3 * hw;
  int B = Bthr[p];
  int shift = 2 * (8 - lvl);
  const float* src = obj.p[lvl] + (size_t)img * n;
  unsigned long long* dst = ck + (size_t)p * CAND_CAP;
  int lane = threadIdx.x & 63;
  for (int e = blockIdx.x * 256 + threadIdx.x; e < n; e += gridDim.x * 256) {
    float v = src[e];
    unsigned sv = fsortkey(v);
    bool pass = (int)(sv >> 20) >= B;
    unsigned long long m = __ballot(pass);
    if (m) {
      int leader = __ffsll(m) - 1;
      unsigned base = 0;
      if (lane == leader) base = atomicAdd(&cnt[p], (unsigned)__popcll(m));
      base = __shfl(base, leader);
      if (pass) {
        unsigned pos = base + (unsigned)__popcll(m & ((1ULL << lane) - 1ULL));
        if (pos < CAND_CAP) {
          int a = e >> shift;            // e / hw
          int r = e & (hw - 1);          // e % hw
          unsigned kidx = (unsigned)(r * 3 + a);   // reference flatten order (y*W+x)*A + a
          dst[pos] = ((unsigned long long)sv << 32) | (unsigned)(0xFFFFFFFFu - kidx);
        }
      }
    }
  }
}

// ------- exact top-kk per level by rank counting, LDS-staged keys ----------------------
__global__ __launch_bounds__(256) void k_select(const unsigned* cnt, const unsigned long long* ck,
                                                unsigned* selSV, unsigned* selIdx) {
  int p = blockIdx.y; int img = p / 5, lvl = p % 5;
  int Cc = min((int)cnt[p], CAND_CAP);
  if (blockIdx.x * 256 >= Cc) return;
  int kk = (lvl == 4) ? 768 : 1000;
  int soff = lvl * 1000;
  const unsigned long long* keys = ck + (size_t)p * CAND_CAP;
  __shared__ unsigned long long sk[4096];
  int stage = min(Cc, 4096);
  for (int j = threadIdx.x; j < stage; j += 256) sk[j] = keys[j];
  __syncthreads();
  int c = blockIdx.x * 256 + threadIdx.x;
  if (c >= Cc) return;
  unsigned long long kc = keys[c];
  int rank = 0;
#pragma unroll 8
  for (int j = 0; j < stage; ++j) rank += (sk[j] > kc) ? 1 : 0;
  for (int j = stage; j < Cc; ++j) rank += (keys[j] > kc) ? 1 : 0;
  if (rank < kk) {
    int slot = img * K_SEL + soff + rank;
    selSV[slot]  = (unsigned)(kc >> 32);
    selIdx[slot] = 0xFFFFFFFFu - (unsigned)kc;
  }
}

// ---------------- decode + clip + validity for the 4768 selected per image --------------
__global__ __launch_bounds__(256) void k_decode(P5 del, const float* anchors,
                                                const unsigned* selSV, const unsigned* selIdx,
                                                float* boxP, unsigned long long* keyP) {
  int i = blockIdx.x * 256 + threadIdx.x;
  if (i >= K_SEL) return;
  int img = blockIdx.y;
  int lvl = (i < 4000) ? (i / 1000) : 4;
  int f = 256 >> lvl, hw = f * f;
  const int aoffA[5] = {0, 196608, 245760, 258048, 261120};
  int slot = img * K_SEL + i;
  unsigned k = selIdx[slot];
  unsigned sv = selSV[slot];
  int a = (int)(k % 3u); int r = (int)(k / 3u);
  int y = r >> (8 - lvl); int x = r & (f - 1);
  const float* dp = del.p[lvl] + (size_t)(img * 12 + a * 4) * hw + (size_t)y * f + x;
  float d0 = dp[0], d1 = dp[hw], d2 = dp[2 * hw], d3 = dp[3 * hw];
  const float* ar = anchors + (size_t)(aoffA[lvl] + (int)k) * 4;
  float a0 = ar[0], a1 = ar[1], a2 = ar[2], a3 = ar[3];
  // numpy-faithful, no FMA contraction
  float w = __fsub_rn(a2, a0), h = __fsub_rn(a3, a1);
  float cx = __fadd_rn(a0, __fmul_rn(0.5f, w));
  float cy = __fadd_rn(a1, __fmul_rn(0.5f, h));
  const float CLIP = 4.135166556742356f;     // log(1000/16)
  float dw = fminf(d2, CLIP), dh = fminf(d3, CLIP);
  float pcx = __fadd_rn(__fmul_rn(d0, w), cx);
  float pcy = __fadd_rn(__fmul_rn(d1, h), cy);
  float pw = __fmul_rn(expf(dw), w);
  float ph = __fmul_rn(expf(dh), h);
  float x1 = __fsub_rn(pcx, __fmul_rn(0.5f, pw));
  float y1 = __fsub_rn(pcy, __fmul_rn(0.5f, ph));
  float x2 = __fadd_rn(pcx, __fmul_rn(0.5f, pw));
  float y2 = __fadd_rn(pcy, __fmul_rn(0.5f, ph));
  float x1c = fminf(fmaxf(x1, 0.0f), 1024.0f);
  float y1c = fminf(fmaxf(y1, 0.0f), 1024.0f);
  float x2c = fminf(fmaxf(x2, 0.0f), 1024.0f);
  float y2c = fminf(fmaxf(y2, 0.0f), 1024.0f);
  bool valid = (__fsub_rn(x2c, x1c) >= 1e-3f) && (__fsub_rn(y2c, y1c) >= 1e-3f);
  float* bp = boxP + (size_t)slot * 4;
  bp[0] = x1c; bp[1] = y1c; bp[2] = x2c; bp[3] = y2c;
  unsigned low = 0xFFFFFFFFu - (unsigned)i;   // pos asc tie-break, unique keys
  keyP[slot] = valid ? (((unsigned long long)sv << 32) | low) : (unsigned long long)low;
}

// ------- global per-image stable sort; also precompute OFFSET boxes + areas -------------
__global__ __launch_bounds__(256) void k_sortrank(const unsigned long long* keyP, const float* boxP,
                                                  float* sBox, unsigned* sMeta,
                                                  float4* oBox4, float* oArea) {
  __shared__ unsigned long long lk[K_SEL];
  int img = blockIdx.y;
  for (int t = threadIdx.x; t < K_SEL; t += 256) lk[t] = keyP[(size_t)img * K_SEL + t];
  __syncthreads();
  int i = blockIdx.x * 256 + threadIdx.x;
  if (i >= K_SEL) return;
  unsigned long long ki = lk[i];
  int rank = 0;
#pragma unroll 8
  for (int j = 0; j < K_SEL; ++j) rank += (lk[j] > ki) ? 1 : 0;
  int slot = img * K_SEL + i;
  const float* bp = boxP + (size_t)slot * 4;
  float b0 = bp[0], b1 = bp[1], b2 = bp[2], b3 = bp[3];
  int oslot = img * K_SEL + rank;
  float* op = sBox + (size_t)oslot * 4;
  op[0] = b0; op[1] = b1; op[2] = b2; op[3] = b3;
  bool valid = (ki >> 32) != 0ULL;
  int pos = (int)(0xFFFFFFFFu - (unsigned)ki);
  int lvl = (pos < 4000) ? pos / 1000 : 4;
  unsigned mval = valid ? (unsigned)lvl : 255u;
  sMeta[oslot] = mval;
  float off = __fmul_rn((float)mval, 1025.0f);
  float ox1 = __fadd_rn(b0, off), oy1 = __fadd_rn(b1, off);
  float ox2 = __fadd_rn(b2, off), oy2 = __fadd_rn(b3, off);
  oBox4[oslot] = make_float4(ox1, oy1, ox2, oy2);
  oArea[oslot] = __fmul_rn(__fsub_rn(ox2, ox1), __fsub_rn(oy2, oy1));
}

// ---------------- IoU on precomputed offset boxes, bitwise matching reference -----------
__device__ __forceinline__ bool iou_gt(float rx1, float ry1, float rx2, float ry2, float rar,
                                       float cx1, float cy1, float cx2, float cy2, float car) {
  float ltx = fmaxf(rx1, cx1), lty = fmaxf(ry1, cy1);
  float rbx = fminf(rx2, cx2), rby = fminf(ry2, cy2);
  float wx = fmaxf(__fsub_rn(rbx, ltx), 0.0f);
  float wy = fmaxf(__fsub_rn(rby, lty), 0.0f);
  float inter = __fmul_rn(wx, wy);
  float denom = __fadd_rn(__fsub_rn(__fadd_rn(rar, car), inter), 1e-9f);
  return __fdiv_rn(inter, denom) > 0.7f;
}

// ---- upper-triangle suppression bitmask, ROW-MAJOR store mask[i][c] --------------------
__global__ __launch_bounds__(256) void k_mask(const float4* oBox4, const float* oArea,
                                              unsigned long long* maskR) {
  int img = blockIdx.y;
  int q = blockIdx.x;                        // 0..740: (R,colb) with colb >= 4R
  int R = (int)((77.0f - sqrtf(5929.0f - 8.0f * (float)q)) * 0.25f);
  while (77 * (R + 1) - 2 * (R + 1) * (R + 1) <= q) ++R;
  while (77 * R - 2 * R * R > q) --R;
  int colb = 4 * R + (q - (77 * R - 2 * R * R));
  int tid = threadIdx.x;
  int w = tid >> 6, t = tid & 63;
  __shared__ float cx1[64], cy1[64], cx2[64], cy2[64], car[64];
  if (tid < 64) {
    int j = colb * 64 + tid;
    if (j < K_SEL) {
      float4 ob = oBox4[(size_t)img * K_SEL + j];
      cx1[tid] = ob.x; cy1[tid] = ob.y; cx2[tid] = ob.z; cy2[tid] = ob.w;
      car[tid] = oArea[(size_t)img * K_SEL + j];
    }
  }
  __syncthreads();
  int rowb = 4 * R + w;
  if (rowb > colb) return;
  int i = rowb * 64 + t;
  if (i >= K_SEL) return;
  float4 rb = oBox4[(size_t)img * K_SEL + i];
  float rar = oArea[(size_t)img * K_SEL + i];
  unsigned long long bits = 0;
  int jmax = min(64, K_SEL - colb * 64);
  int jj0 = (rowb == colb) ? t + 1 : 0;
  for (int jj = jj0; jj < jmax; ++jj) {
    if (iou_gt(rb.x, rb.y, rb.z, rb.w, rar, cx1[jj], cy1[jj], cx2[jj], cy2[jj], car[jj]))
      bits |= (1ULL << jj);
  }
  maskR[((size_t)img * K_SEL + i) * W75 + colb] = bits;   // row-major (scan reads rows coalesced)
}

// --- single-wave bit-scan; exact speculation: issue kept-candidate row loads BEFORE -----
// --- the serial loop (candm0 needs only registers), fold from landed registers. ---------
// remv distributed: lane t owns word t (r0) and word 64+t (r1, t<11).
__global__ __launch_bounds__(64) void k_scan(const float* sBox, const unsigned* sMeta,
                                             const unsigned long long* maskR, float* out) {
  int img = blockIdx.x;
  int t = threadIdx.x;
  const unsigned long long* mb = maskR + (size_t)img * K_SEL * W75;
  const float4* boxes4 = (const float4*)(sBox + (size_t)img * K_SEL * 4);
  float4* out4 = (float4*)(out + (size_t)img * 1000 * 4);
  const unsigned* meta = sMeta + (size_t)img * K_SEL;
  unsigned long long r0 = 0ULL, r1 = 0ULL;
  const bool hasw1 = t < (W75 - 64);
  int outc = 0;
  unsigned mv = meta[t];                                  // prefetch chunk 0
  unsigned long long wpre = mb[(size_t)t * W75 + 0];
  for (int c = 0; c < W75; ++c) {
    int i = c * 64 + t;
    bool inb = i < K_SEL;
    unsigned long long validm = __ballot(inb && (mv != 255u));
    unsigned long long wcur = wpre;
    int cn = (c + 1 < W75) ? c + 1 : c;                   // prefetch next chunk (keep-independent)
    int inx = cn * 64 + t; if (inx >= K_SEL) inx = K_SEL - 1;
    mv = meta[inx];
    wpre = mb[(size_t)inx * W75 + cn];
    unsigned long long cur = (c < 64) ? __shfl(r0, c) : __shfl(r1, c - 64);
    unsigned long long candm0 = validm & ~cur;
    // --- speculative coalesced row loads for the first SPEC candidates ---
    int rows[SPEC];
    unsigned long long covered = 0ULL;
    {
      unsigned long long cm = candm0;
#pragma unroll
      for (int k = 0; k < SPEC; ++k) {
        if (cm) { int b = __ffsll(cm) - 1; rows[k] = b; covered |= (1ULL << b); cm &= cm - 1; }
        else rows[k] = -1;
      }
    }
    int cbase = c * 64;
    unsigned long long sv0[SPEC], sv1[SPEC];
#pragma unroll
    for (int k = 0; k < SPEC; ++k) {
      const unsigned long long* rp = mb + (size_t)(cbase + (rows[k] >= 0 ? rows[k] : 0)) * W75;
      sv0[k] = (rows[k] >= 0) ? rp[t] : 0ULL;             // lane t = word t: coalesced
      sv1[k] = (rows[k] >= 0 && hasw1) ? rp[64 + t] : 0ULL;
    }
    // --- serial greedy within chunk: registers only, overlaps the loads above ---
    unsigned long long candm = candm0;
    unsigned long long keepm = 0ULL;
    int base = outc;
    while (candm) {
      int b = __ffsll(candm) - 1;
      keepm |= (1ULL << b);
      ++outc;
      if (outc == 1000) break;
      candm &= candm - 1;
      candm &= ~__shfl(wcur, b);                          // within-chunk suppression
    }
    if ((keepm >> t) & 1ULL) {
      int rank = (int)__popcll(keepm & ((1ULL << t) - 1ULL));
      out4[base + rank] = boxes4[i];
    }
    if (outc >= 1000) { outc = 1000; break; }
    // --- fold kept rows from speculative registers (waitcnt lands here) ---
#pragma unroll
    for (int k = 0; k < SPEC; ++k) {
      bool take = (rows[k] >= 0) && ((keepm >> (rows[k] & 63)) & 1ULL);
      r0 |= take ? sv0[k] : 0ULL;
      r1 |= take ? sv1[k] : 0ULL;
    }
    unsigned long long un = keepm & ~covered;             // rare: keeps beyond SPEC
    while (un) {
      int b = __ffsll(un) - 1; un &= un - 1;
      const unsigned long long* rp = mb + (size_t)(cbase + b) * W75;
      r0 |= rp[t];
      if (hasw1) r1 |= rp[64 + t];
    }
    // garbage in lower-triangle words (< c) only ORs into already-consumed remv words.
  }
  for (int s = outc + t; s < 1000; s += 64)
    out4[s] = make_float4(0.f, 0.f, 0.f, 0.f);            // zero-pad tail (replaces memset)
}

// ---------------- path B fallback (small ws): barrier-sequential NMS --------------------
__global__ __launch_bounds__(256) void k_nmsseq(const float* sBox, const unsigned* sMeta,
                                                float* out) {
  int img = blockIdx.x;
  int t = threadIdx.x;
  __shared__ unsigned char keep[K_SEL];
  for (int i = t; i < K_SEL; i += 256) keep[i] = (sMeta[img * K_SEL + i] != 255u) ? 1 : 0;
  __syncthreads();
  for (int i = 0; i < K_SEL; ++i) {
    __syncthreads();
    if (!keep[i]) continue;
    unsigned lvi = sMeta[img * K_SEL + i];
    const float* bp = sBox + (size_t)(img * K_SEL + i) * 4;
    float off = __fmul_rn((float)lvi, 1025.0f);
    float rx1 = __fadd_rn(bp[0], off), ry1 = __fadd_rn(bp[1], off);
    float rx2 = __fadd_rn(bp[2], off), ry2 = __fadd_rn(bp[3], off);
    float rar = __fmul_rn(__fsub_rn(rx2, rx1), __fsub_rn(ry2, ry1));
    for (int j = i + 1 + t; j < K_SEL; j += 256) {
      if (!keep[j]) continue;
      unsigned lvj = sMeta[img * K_SEL + j];
      if (lvj != lvi) continue;
      const float* bq = sBox + (size_t)(img * K_SEL + j) * 4;
      float qx1 = __fadd_rn(bq[0], off), qy1 = __fadd_rn(bq[1], off);
      float qx2 = __fadd_rn(bq[2], off), qy2 = __fadd_rn(bq[3], off);
      float qar = __fmul_rn(__fsub_rn(qx2, qx1), __fsub_rn(qy2, qy1));
      if (iou_gt(rx1, ry1, rx2, ry2, rar, qx1, qy1, qx2, qy2, qar)) keep[j] = 0;
    }
  }
  __syncthreads();
  if (t == 0) {
    int outc = 0;
    for (int i = 0; i < K_SEL && outc < 1000; ++i) {
      if (!keep[i]) continue;
      const float* bp = sBox + (size_t)(img * K_SEL + i) * 4;
      float* op = out + ((size_t)img * 1000 + outc) * 4;
      op[0] = bp[0]; op[1] = bp[1]; op[2] = bp[2]; op[3] = bp[3];
      ++outc;
    }
  }
}

extern "C" void kernel_launch(void* const* d_in, const int* in_sizes, int n_in,
                              void* d_out, int out_size, void* d_ws, size_t ws_size,
                              hipStream_t stream) {
  (void)in_sizes; (void)n_in;
  // setup_inputs() dict order is INTERLEAVED: obj_l0, delta_l0, obj_l1, delta_l1, ..., anchors
  P5 obj, del;
  for (int i = 0; i < 5; ++i) {
    obj.p[i] = (const float*)d_in[2 * i];
    del.p[i] = (const float*)d_in[2 * i + 1];
  }
  const float* anchors = (const float*)d_in[10];
  float* out = (float*)d_out;
  char* ws = (char*)d_ws;

  // ws layout (bytes)
  unsigned* cnt               = (unsigned*)(ws + 655360);              // 160
  int* Bthr                   = (int*)(ws + 655520);                   // 160
  unsigned long long* candK   = (unsigned long long*)(ws + 655680);    // 40*16384*8 = 5242880
  // oBox4/oArea reuse the candK region (dead after k_select)
  float4* oBox4               = (float4*)(ws + 655680);                // 8*4768*16 = 610304
  float* oArea                = (float*)(ws + 1265984);                // 8*4768*4  = 152576
  unsigned* selSV             = (unsigned*)(ws + 5898560);             // 152576
  unsigned* selIdx            = (unsigned*)(ws + 6051136);             // 152576
  float* boxP                 = (float*)(ws + 6203712);                // 610304
  unsigned long long* keyP    = (unsigned long long*)(ws + 6814016);   // 305152
  float* sBox                 = (float*)(ws + 7119168);                // 610304
  unsigned* sMeta             = (unsigned*)(ws + 7729472);             // 152576
  unsigned long long* maskR   = (unsigned long long*)(ws + 7882048);   // 8*4768*75*8 = 22878720
  unsigned* phist             = (unsigned*)(ws + 7882048);             // overlay on maskR: 40*8*4096*4 = 5242880 (dead before k_mask)
  const size_t NEED_A = 30760768ULL;   // through maskR
  const size_t NEED_B = 13124928ULL;   // through phist overlay, no full maskR
  bool pathA = ws_size >= NEED_A;
  bool pathB = !pathA && ws_size >= NEED_B;

  if (!pathA && !pathB) { hipMemsetAsync(d_out, 0, (size_t)out_size * 4, stream); return; }
  if (!pathA) hipMemsetAsync(d_out, 0, (size_t)out_size * 4, stream);   // pathA zero-fills in k_scan

  k_hist   <<<dim3(8, 40), 256, 0, stream>>>(obj, phist);
  k_thresh <<<40, 256, 0, stream>>>(phist, Bthr, cnt);
  k_gather <<<dim3(64, 40), 256, 0, stream>>>(obj, Bthr, cnt, candK);
  k_select <<<dim3(64, 40), 256, 0, stream>>>(cnt, candK, selSV, selIdx);
  k_decode <<<dim3(19, 8), 256, 0, stream>>>(del, anchors, selSV, selIdx, boxP, keyP);
  k_sortrank<<<dim3(19, 8), 256, 0, stream>>>(keyP, boxP, sBox, sMeta, oBox4, oArea);
  if (pathA) {
    k_mask <<<dim3(741, 8), 256, 0, stream>>>(oBox4, oArea, maskR);
    k_scan <<<8, 64, 0, stream>>>(sBox, sMeta, maskR, out);
  } else {
    k_nmsseq<<<8, 256, 0, stream>>>(sBox, sMeta, out);
  }
}

// Round 8
// 681.607 us; speedup vs baseline: 1.2020x; 1.2020x over previous
//
#include <hip/hip_runtime.h>
#include <cstdint>

#define K_SEL 4768
#define W75 75
#define CAND_CAP 16384
#define NBIN 4096

struct P5 { const float* p[5]; };

__device__ __forceinline__ unsigned fsortkey(float f) {
  unsigned b = __float_as_uint(f);
  return (b & 0x80000000u) ? ~b : (b | 0x80000000u);
}

// ------- histogram of sortable-logit top-12 bits per (img,lvl): per-block partials ------
__global__ __launch_bounds__(256) void k_hist(P5 obj, unsigned* phist) {
  int p = blockIdx.y; int img = p / 5, lvl = p % 5;
  int f = 256 >> lvl; int n = 3 * f * f;
  __shared__ unsigned lh[NBIN];
  for (int b = threadIdx.x; b < NBIN; b += 256) lh[b] = 0;
  __syncthreads();
  int chunk = (n + gridDim.x - 1) / gridDim.x;
  int e0 = blockIdx.x * chunk, e1 = min(n, e0 + chunk);
  const float* src = obj.p[lvl] + (size_t)img * n;
  for (int e = e0 + threadIdx.x; e < e1; e += 256) {
    unsigned sv = fsortkey(src[e]);
    atomicAdd(&lh[sv >> 20], 1u);
  }
  __syncthreads();
  unsigned* dst = phist + ((size_t)(p * 8 + blockIdx.x)) * NBIN;
  for (int b = threadIdx.x; b < NBIN; b += 256) dst[b] = lh[b];   // unconditional: no pre-zero
}

// ------- sum partials, find threshold bin B (count(bin >= B) >= kk), zero cnt ----------
__global__ __launch_bounds__(256) void k_thresh(const unsigned* phist, int* Bthr, unsigned* cnt) {
  int p = blockIdx.x; int lvl = p % 5;
  unsigned kk = (lvl == 4) ? 768u : 1000u;
  __shared__ unsigned hsum[NBIN];
  __shared__ unsigned csum[256];
  int c = threadIdx.x;
  unsigned tot[16];
#pragma unroll
  for (int k = 0; k < 16; ++k) tot[k] = 0;
  for (int g = 0; g < 8; ++g) {
    const unsigned* hp = phist + ((size_t)(p * 8 + g)) * NBIN + c * 16;
#pragma unroll
    for (int k = 0; k < 16; ++k) tot[k] += hp[k];
  }
  unsigned s = 0;
#pragma unroll
  for (int k = 0; k < 16; ++k) { hsum[c * 16 + k] = tot[k]; s += tot[k]; }
  csum[c] = s;
  __syncthreads();
  if (c == 0) {
    unsigned acc = 0; int B = 0;
    for (int cc = 255; cc >= 0; --cc) {
      if (acc + csum[cc] >= kk) {
        for (int b = 15; b >= 0; --b) {
          acc += hsum[cc * 16 + b];
          if (acc >= kk) { B = cc * 16 + b; break; }
        }
        break;
      }
      acc += csum[cc];
    }
    Bthr[p] = B;
    cnt[p] = 0;                              // replaces ws memset for gather's counter
  }
}

// ------- gather candidates (bin >= B), wave-aggregated atomics, grid-stride ------------
__global__ __launch_bounds__(256) void k_gather(P5 obj, const int* Bthr, unsigned* cnt,
                                                unsigned long long* ck) {
  int p = blockIdx.y; int img = p / 5, lvl = p % 5;
  int f = 256 >> lvl; int hw = f * f; int n = 3 * hw;
  int B = Bthr[p];
  int shift = 2 * (8 - lvl);
  const float* src = obj.p[lvl] + (size_t)img * n;
  unsigned long long* dst = ck + (size_t)p * CAND_CAP;
  int lane = threadIdx.x & 63;
  for (int e = blockIdx.x * 256 + threadIdx.x; e < n; e += gridDim.x * 256) {
    float v = src[e];
    unsigned sv = fsortkey(v);
    bool pass = (int)(sv >> 20) >= B;
    unsigned long long m = __ballot(pass);
    if (m) {
      int leader = __ffsll(m) - 1;
      unsigned base = 0;
      if (lane == leader) base = atomicAdd(&cnt[p], (unsigned)__popcll(m));
      base = __shfl(base, leader);
      if (pass) {
        unsigned pos = base + (unsigned)__popcll(m & ((1ULL << lane) - 1ULL));
        if (pos < CAND_CAP) {
          int a = e >> shift;            // e / hw
          int r = e & (hw - 1);          // e % hw
          unsigned kidx = (unsigned)(r * 3 + a);   // reference flatten order (y*W+x)*A + a
          dst[pos] = ((unsigned long long)sv << 32) | (unsigned)(0xFFFFFFFFu - kidx);
        }
      }
    }
  }
}

// ------- exact top-kk per level by rank counting, LDS-staged keys ----------------------
__global__ __launch_bounds__(256) void k_select(const unsigned* cnt, const unsigned long long* ck,
                                                unsigned* selSV, unsigned* selIdx) {
  int p = blockIdx.y; int img = p / 5, lvl = p % 5;
  int Cc = min((int)cnt[p], CAND_CAP);
  if (blockIdx.x * 256 >= Cc) return;
  int kk = (lvl == 4) ? 768 : 1000;
  int soff = lvl * 1000;
  const unsigned long long* keys = ck + (size_t)p * CAND_CAP;
  __shared__ unsigned long long sk[4096];
  int stage = min(Cc, 4096);
  for (int j = threadIdx.x; j < stage; j += 256) sk[j] = keys[j];
  __syncthreads();
  int c = blockIdx.x * 256 + threadIdx.x;
  if (c >= Cc) return;
  unsigned long long kc = keys[c];
  int rank = 0;
#pragma unroll 8
  for (int j = 0; j < stage; ++j) rank += (sk[j] > kc) ? 1 : 0;
  for (int j = stage; j < Cc; ++j) rank += (keys[j] > kc) ? 1 : 0;
  if (rank < kk) {
    int slot = img * K_SEL + soff + rank;
    selSV[slot]  = (unsigned)(kc >> 32);
    selIdx[slot] = 0xFFFFFFFFu - (unsigned)kc;
  }
}

// ---------------- decode + clip + validity for the 4768 selected per image --------------
__global__ __launch_bounds__(256) void k_decode(P5 del, const float* anchors,
                                                const unsigned* selSV, const unsigned* selIdx,
                                                float* boxP, unsigned long long* keyP) {
  int i = blockIdx.x * 256 + threadIdx.x;
  if (i >= K_SEL) return;
  int img = blockIdx.y;
  int lvl = (i < 4000) ? (i / 1000) : 4;
  int f = 256 >> lvl, hw = f * f;
  const int aoffA[5] = {0, 196608, 245760, 258048, 261120};
  int slot = img * K_SEL + i;
  unsigned k = selIdx[slot];
  unsigned sv = selSV[slot];
  int a = (int)(k % 3u); int r = (int)(k / 3u);
  int y = r >> (8 - lvl); int x = r & (f - 1);
  const float* dp = del.p[lvl] + (size_t)(img * 12 + a * 4) * hw + (size_t)y * f + x;
  float d0 = dp[0], d1 = dp[hw], d2 = dp[2 * hw], d3 = dp[3 * hw];
  const float* ar = anchors + (size_t)(aoffA[lvl] + (int)k) * 4;
  float a0 = ar[0], a1 = ar[1], a2 = ar[2], a3 = ar[3];
  // numpy-faithful, no FMA contraction
  float w = __fsub_rn(a2, a0), h = __fsub_rn(a3, a1);
  float cx = __fadd_rn(a0, __fmul_rn(0.5f, w));
  float cy = __fadd_rn(a1, __fmul_rn(0.5f, h));
  const float CLIP = 4.135166556742356f;     // log(1000/16)
  float dw = fminf(d2, CLIP), dh = fminf(d3, CLIP);
  float pcx = __fadd_rn(__fmul_rn(d0, w), cx);
  float pcy = __fadd_rn(__fmul_rn(d1, h), cy);
  float pw = __fmul_rn(expf(dw), w);
  float ph = __fmul_rn(expf(dh), h);
  float x1 = __fsub_rn(pcx, __fmul_rn(0.5f, pw));
  float y1 = __fsub_rn(pcy, __fmul_rn(0.5f, ph));
  float x2 = __fadd_rn(pcx, __fmul_rn(0.5f, pw));
  float y2 = __fadd_rn(pcy, __fmul_rn(0.5f, ph));
  float x1c = fminf(fmaxf(x1, 0.0f), 1024.0f);
  float y1c = fminf(fmaxf(y1, 0.0f), 1024.0f);
  float x2c = fminf(fmaxf(x2, 0.0f), 1024.0f);
  float y2c = fminf(fmaxf(y2, 0.0f), 1024.0f);
  bool valid = (__fsub_rn(x2c, x1c) >= 1e-3f) && (__fsub_rn(y2c, y1c) >= 1e-3f);
  float* bp = boxP + (size_t)slot * 4;
  bp[0] = x1c; bp[1] = y1c; bp[2] = x2c; bp[3] = y2c;
  unsigned low = 0xFFFFFFFFu - (unsigned)i;   // pos asc tie-break, unique keys
  keyP[slot] = valid ? (((unsigned long long)sv << 32) | low) : (unsigned long long)low;
}

// ------- global per-image stable sort; also precompute OFFSET boxes + areas -------------
__global__ __launch_bounds__(256) void k_sortrank(const unsigned long long* keyP, const float* boxP,
                                                  float* sBox, unsigned* sMeta,
                                                  float4* oBox4, float* oArea) {
  __shared__ unsigned long long lk[K_SEL];
  int img = blockIdx.y;
  for (int t = threadIdx.x; t < K_SEL; t += 256) lk[t] = keyP[(size_t)img * K_SEL + t];
  __syncthreads();
  int i = blockIdx.x * 256 + threadIdx.x;
  if (i >= K_SEL) return;
  unsigned long long ki = lk[i];
  int rank = 0;
#pragma unroll 8
  for (int j = 0; j < K_SEL; ++j) rank += (lk[j] > ki) ? 1 : 0;
  int slot = img * K_SEL + i;
  const float* bp = boxP + (size_t)slot * 4;
  float b0 = bp[0], b1 = bp[1], b2 = bp[2], b3 = bp[3];
  int oslot = img * K_SEL + rank;
  float* op = sBox + (size_t)oslot * 4;
  op[0] = b0; op[1] = b1; op[2] = b2; op[3] = b3;
  bool valid = (ki >> 32) != 0ULL;
  int pos = (int)(0xFFFFFFFFu - (unsigned)ki);
  int lvl = (pos < 4000) ? pos / 1000 : 4;
  unsigned mval = valid ? (unsigned)lvl : 255u;
  sMeta[oslot] = mval;
  float off = __fmul_rn((float)mval, 1025.0f);
  float ox1 = __fadd_rn(b0, off), oy1 = __fadd_rn(b1, off);
  float ox2 = __fadd_rn(b2, off), oy2 = __fadd_rn(b3, off);
  oBox4[oslot] = make_float4(ox1, oy1, ox2, oy2);
  oArea[oslot] = __fmul_rn(__fsub_rn(ox2, ox1), __fsub_rn(oy2, oy1));
}

// ---------------- IoU on precomputed offset boxes, bitwise matching reference -----------
__device__ __forceinline__ bool iou_gt(float rx1, float ry1, float rx2, float ry2, float rar,
                                       float cx1, float cy1, float cx2, float cy2, float car) {
  float ltx = fmaxf(rx1, cx1), lty = fmaxf(ry1, cy1);
  float rbx = fminf(rx2, cx2), rby = fminf(ry2, cy2);
  float wx = fmaxf(__fsub_rn(rbx, ltx), 0.0f);
  float wy = fmaxf(__fsub_rn(rby, lty), 0.0f);
  float inter = __fmul_rn(wx, wy);
  float denom = __fadd_rn(__fsub_rn(__fadd_rn(rar, car), inter), 1e-9f);
  return __fdiv_rn(inter, denom) > 0.7f;
}

// ---- upper-triangle suppression bitmask, ROW-MAJOR store mask[i][c] --------------------
__global__ __launch_bounds__(256) void k_mask(const float4* oBox4, const float* oArea,
                                              unsigned long long* maskR) {
  int img = blockIdx.y;
  int q = blockIdx.x;                        // 0..740: (R,colb) with colb >= 4R
  int R = (int)((77.0f - sqrtf(5929.0f - 8.0f * (float)q)) * 0.25f);
  while (77 * (R + 1) - 2 * (R + 1) * (R + 1) <= q) ++R;
  while (77 * R - 2 * R * R > q) --R;
  int colb = 4 * R + (q - (77 * R - 2 * R * R));
  int tid = threadIdx.x;
  int w = tid >> 6, t = tid & 63;
  __shared__ float cx1[64], cy1[64], cx2[64], cy2[64], car[64];
  if (tid < 64) {
    int j = colb * 64 + tid;
    if (j < K_SEL) {
      float4 ob = oBox4[(size_t)img * K_SEL + j];
      cx1[tid] = ob.x; cy1[tid] = ob.y; cx2[tid] = ob.z; cy2[tid] = ob.w;
      car[tid] = oArea[(size_t)img * K_SEL + j];
    }
  }
  __syncthreads();
  int rowb = 4 * R + w;
  if (rowb > colb) return;
  int i = rowb * 64 + t;
  if (i >= K_SEL) return;
  float4 rb = oBox4[(size_t)img * K_SEL + i];
  float rar = oArea[(size_t)img * K_SEL + i];
  unsigned long long bits = 0;
  int jmax = min(64, K_SEL - colb * 64);
  int jj0 = (rowb == colb) ? t + 1 : 0;
  for (int jj = jj0; jj < jmax; ++jj) {
    if (iou_gt(rb.x, rb.y, rb.z, rb.w, rar, cx1[jj], cy1[jj], cx2[jj], cy2[jj], car[jj]))
      bits |= (1ULL << jj);
  }
  maskR[((size_t)img * K_SEL + i) * W75 + colb] = bits;   // row-major (scan folds read rows coalesced)
}

// --- single-wave bit-scan; register-distributed remv + row-major coalesced folds --------
// lane t owns suppression word t (r0) and word 64+t (r1, t<11). Folds happen AFTER keepm
// is known: batches of 8 kept rows, each row read coalesced (lane t = word t), predicated
// on word > c (words <= c are never re-read; also skips unwritten lower-triangle words).
__global__ __launch_bounds__(64) void k_scan(const float* sBox, const unsigned* sMeta,
                                             const unsigned long long* maskR, float* out) {
  int img = blockIdx.x;
  int t = threadIdx.x;
  const unsigned long long* mb = maskR + (size_t)img * K_SEL * W75;
  const float4* boxes4 = (const float4*)(sBox + (size_t)img * K_SEL * 4);
  float4* out4 = (float4*)(out + (size_t)img * 1000 * 4);
  const unsigned* meta = sMeta + (size_t)img * K_SEL;
  unsigned long long r0 = 0ULL, r1 = 0ULL;
  const bool hasw1 = t < (W75 - 64);
  int outc = 0;
  unsigned mv = meta[t];                                  // prefetch chunk 0
  unsigned long long wpre = mb[(size_t)t * W75 + 0];
  for (int c = 0; c < W75; ++c) {
    int i = c * 64 + t;
    bool inb = i < K_SEL;
    unsigned long long validm = __ballot(inb && (mv != 255u));
    unsigned long long wcur = wpre;
    int cn = (c + 1 < W75) ? c + 1 : c;                   // prefetch next chunk (keep-independent)
    int inx = cn * 64 + t; if (inx >= K_SEL) inx = K_SEL - 1;
    mv = meta[inx];
    wpre = mb[(size_t)inx * W75 + cn];
    unsigned long long cur = (c < 64) ? __shfl(r0, c) : __shfl(r1, c - 64);
    unsigned long long candm = validm & ~cur;
    unsigned long long keepm = 0ULL;
    int base = outc;
    while (candm) {
      int b = __ffsll(candm) - 1;
      keepm |= (1ULL << b);
      ++outc;
      if (outc == 1000) break;
      candm &= candm - 1;
      candm &= ~__shfl(wcur, b);                          // within-chunk suppression
    }
    if ((keepm >> t) & 1ULL) {
      int rank = (int)__popcll(keepm & ((1ULL << t) - 1ULL));
      out4[base + rank] = boxes4[i];
    }
    if (outc >= 1000) { outc = 1000; break; }
    // fold kept rows: batches of 8 independent COALESCED row loads, one wait per batch
    const bool need0 = t > c;                             // word t needed only if > c
    const bool need1 = hasw1 && (64 + t > c);
    int cbase = c * 64;
    unsigned long long km = keepm;
    while (km) {
      int bs[8];
#pragma unroll
      for (int k = 0; k < 8; ++k) {
        if (km) { bs[k] = __ffsll(km) - 1; km &= km - 1; } else bs[k] = -1;
      }
      unsigned long long v[8], u[8];
#pragma unroll
      for (int k = 0; k < 8; ++k) {
        const unsigned long long* rp = mb + (size_t)(cbase + (bs[k] >= 0 ? bs[k] : 0)) * W75;
        v[k] = (bs[k] >= 0 && need0) ? rp[t] : 0ULL;      // bs[k]>=0 is wave-uniform
        u[k] = (bs[k] >= 0 && need1) ? rp[64 + t] : 0ULL;
      }
      r0 |= ((v[0] | v[1]) | (v[2] | v[3])) | ((v[4] | v[5]) | (v[6] | v[7]));
      r1 |= ((u[0] | u[1]) | (u[2] | u[3])) | ((u[4] | u[5]) | (u[6] | u[7]));
    }
  }
  for (int s = outc + t; s < 1000; s += 64)
    out4[s] = make_float4(0.f, 0.f, 0.f, 0.f);            // zero-pad tail (replaces memset)
}

// ---------------- path B fallback (small ws): barrier-sequential NMS --------------------
__global__ __launch_bounds__(256) void k_nmsseq(const float* sBox, const unsigned* sMeta,
                                                float* out) {
  int img = blockIdx.x;
  int t = threadIdx.x;
  __shared__ unsigned char keep[K_SEL];
  for (int i = t; i < K_SEL; i += 256) keep[i] = (sMeta[img * K_SEL + i] != 255u) ? 1 : 0;
  __syncthreads();
  for (int i = 0; i < K_SEL; ++i) {
    __syncthreads();
    if (!keep[i]) continue;
    unsigned lvi = sMeta[img * K_SEL + i];
    const float* bp = sBox + (size_t)(img * K_SEL + i) * 4;
    float off = __fmul_rn((float)lvi, 1025.0f);
    float rx1 = __fadd_rn(bp[0], off), ry1 = __fadd_rn(bp[1], off);
    float rx2 = __fadd_rn(bp[2], off), ry2 = __fadd_rn(bp[3], off);
    float rar = __fmul_rn(__fsub_rn(rx2, rx1), __fsub_rn(ry2, ry1));
    for (int j = i + 1 + t; j < K_SEL; j += 256) {
      if (!keep[j]) continue;
      unsigned lvj = sMeta[img * K_SEL + j];
      if (lvj != lvi) continue;
      const float* bq = sBox + (size_t)(img * K_SEL + j) * 4;
      float qx1 = __fadd_rn(bq[0], off), qy1 = __fadd_rn(bq[1], off);
      float qx2 = __fadd_rn(bq[2], off), qy2 = __fadd_rn(bq[3], off);
      float qar = __fmul_rn(__fsub_rn(qx2, qx1), __fsub_rn(qy2, qy1));
      if (iou_gt(rx1, ry1, rx2, ry2, rar, qx1, qy1, qx2, qy2, qar)) keep[j] = 0;
    }
  }
  __syncthreads();
  if (t == 0) {
    int outc = 0;
    for (int i = 0; i < K_SEL && outc < 1000; ++i) {
      if (!keep[i]) continue;
      const float* bp = sBox + (size_t)(img * K_SEL + i) * 4;
      float* op = out + ((size_t)img * 1000 + outc) * 4;
      op[0] = bp[0]; op[1] = bp[1]; op[2] = bp[2]; op[3] = bp[3];
      ++outc;
    }
  }
}

extern "C" void kernel_launch(void* const* d_in, const int* in_sizes, int n_in,
                              void* d_out, int out_size, void* d_ws, size_t ws_size,
                              hipStream_t stream) {
  (void)in_sizes; (void)n_in;
  // setup_inputs() dict order is INTERLEAVED: obj_l0, delta_l0, obj_l1, delta_l1, ..., anchors
  P5 obj, del;
  for (int i = 0; i < 5; ++i) {
    obj.p[i] = (const float*)d_in[2 * i];
    del.p[i] = (const float*)d_in[2 * i + 1];
  }
  const float* anchors = (const float*)d_in[10];
  float* out = (float*)d_out;
  char* ws = (char*)d_ws;

  // ws layout (bytes)
  unsigned* cnt               = (unsigned*)(ws + 655360);              // 160
  int* Bthr                   = (int*)(ws + 655520);                   // 160
  unsigned long long* candK   = (unsigned long long*)(ws + 655680);    // 40*16384*8 = 5242880
  // oBox4/oArea reuse the candK region (dead after k_select)
  float4* oBox4               = (float4*)(ws + 655680);                // 8*4768*16 = 610304
  float* oArea                = (float*)(ws + 1265984);                // 8*4768*4  = 152576
  unsigned* selSV             = (unsigned*)(ws + 5898560);             // 152576
  unsigned* selIdx            = (unsigned*)(ws + 6051136);             // 152576
  float* boxP                 = (float*)(ws + 6203712);                // 610304
  unsigned long long* keyP    = (unsigned long long*)(ws + 6814016);   // 305152
  float* sBox                 = (float*)(ws + 7119168);                // 610304
  unsigned* sMeta             = (unsigned*)(ws + 7729472);             // 152576
  unsigned long long* maskR   = (unsigned long long*)(ws + 7882048);   // 8*4768*75*8 = 22878720
  unsigned* phist             = (unsigned*)(ws + 7882048);             // overlay on maskR: 40*8*4096*4 (dead before k_mask)
  const size_t NEED_A = 30760768ULL;   // through maskR
  const size_t NEED_B = 13124928ULL;   // through phist overlay, no full maskR
  bool pathA = ws_size >= NEED_A;
  bool pathB = !pathA && ws_size >= NEED_B;

  if (!pathA && !pathB) { hipMemsetAsync(d_out, 0, (size_t)out_size * 4, stream); return; }
  if (!pathA) hipMemsetAsync(d_out, 0, (size_t)out_size * 4, stream);   // pathA zero-fills in k_scan

  k_hist   <<<dim3(8, 40), 256, 0, stream>>>(obj, phist);
  k_thresh <<<40, 256, 0, stream>>>(phist, Bthr, cnt);
  k_gather <<<dim3(64, 40), 256, 0, stream>>>(obj, Bthr, cnt, candK);
  k_select <<<dim3(64, 40), 256, 0, stream>>>(cnt, candK, selSV, selIdx);
  k_decode <<<dim3(19, 8), 256, 0, stream>>>(del, anchors, selSV, selIdx, boxP, keyP);
  k_sortrank<<<dim3(19, 8), 256, 0, stream>>>(keyP, boxP, sBox, sMeta, oBox4, oArea);
  if (pathA) {
    k_mask <<<dim3(741, 8), 256, 0, stream>>>(oBox4, oArea, maskR);
    k_scan <<<8, 64, 0, stream>>>(sBox, sMeta, maskR, out);
  } else {
    k_nmsseq<<<8, 256, 0, stream>>>(sBox, sMeta, out);
  }
}

// Round 9
// 539.817 us; speedup vs baseline: 1.5177x; 1.2627x over previous
//
#include <hip/hip_runtime.h>
#include <cstdint>

#define K_SEL 4768
#define CAND_CAP 16384
#define NBIN 4096

struct P5 { const float* p[5]; };

__device__ __forceinline__ unsigned fsortkey(float f) {
  unsigned b = __float_as_uint(f);
  return (b & 0x80000000u) ? ~b : (b | 0x80000000u);
}

// ------- histogram of sortable-logit top-12 bits per (img,lvl): per-block partials ------
__global__ __launch_bounds__(256) void k_hist(P5 obj, unsigned* phist) {
  int p = blockIdx.y; int img = p / 5, lvl = p % 5;
  int f = 256 >> lvl; int n = 3 * f * f;
  __shared__ unsigned lh[NBIN];
  for (int b = threadIdx.x; b < NBIN; b += 256) lh[b] = 0;
  __syncthreads();
  int chunk = (n + gridDim.x - 1) / gridDim.x;
  int e0 = blockIdx.x * chunk, e1 = min(n, e0 + chunk);
  const float* src = obj.p[lvl] + (size_t)img * n;
  for (int e = e0 + threadIdx.x; e < e1; e += 256) {
    unsigned sv = fsortkey(src[e]);
    atomicAdd(&lh[sv >> 20], 1u);
  }
  __syncthreads();
  unsigned* dst = phist + ((size_t)(p * 8 + blockIdx.x)) * NBIN;
  for (int b = threadIdx.x; b < NBIN; b += 256) dst[b] = lh[b];   // unconditional: no pre-zero
}

// ------- sum partials, find threshold bin B (count(bin >= B) >= kk), zero cnt ----------
__global__ __launch_bounds__(256) void k_thresh(const unsigned* phist, int* Bthr, unsigned* cnt) {
  int p = blockIdx.x; int lvl = p % 5;
  unsigned kk = (lvl == 4) ? 768u : 1000u;
  __shared__ unsigned hsum[NBIN];
  __shared__ unsigned csum[256];
  int c = threadIdx.x;
  unsigned tot[16];
#pragma unroll
  for (int k = 0; k < 16; ++k) tot[k] = 0;
  for (int g = 0; g < 8; ++g) {
    const unsigned* hp = phist + ((size_t)(p * 8 + g)) * NBIN + c * 16;
#pragma unroll
    for (int k = 0; k < 16; ++k) tot[k] += hp[k];
  }
  unsigned s = 0;
#pragma unroll
  for (int k = 0; k < 16; ++k) { hsum[c * 16 + k] = tot[k]; s += tot[k]; }
  csum[c] = s;
  __syncthreads();
  if (c == 0) {
    unsigned acc = 0; int B = 0;
    for (int cc = 255; cc >= 0; --cc) {
      if (acc + csum[cc] >= kk) {
        for (int b = 15; b >= 0; --b) {
          acc += hsum[cc * 16 + b];
          if (acc >= kk) { B = cc * 16 + b; break; }
        }
        break;
      }
      acc += csum[cc];
    }
    Bthr[p] = B;
    cnt[p] = 0;                              // replaces ws memset for gather's counter
  }
}

// ------- gather candidates (bin >= B), wave-aggregated atomics, grid-stride ------------
__global__ __launch_bounds__(256) void k_gather(P5 obj, const int* Bthr, unsigned* cnt,
                                                unsigned long long* ck) {
  int p = blockIdx.y; int img = p / 5, lvl = p % 5;
  int f = 256 >> lvl; int hw = f * f; int n = 3 * hw;
  int B = Bthr[p];
  int shift = 2 * (8 - lvl);
  const float* src = obj.p[lvl] + (size_t)img * n;
  unsigned long long* dst = ck + (size_t)p * CAND_CAP;
  int lane = threadIdx.x & 63;
  for (int e = blockIdx.x * 256 + threadIdx.x; e < n; e += gridDim.x * 256) {
    float v = src[e];
    unsigned sv = fsortkey(v);
    bool pass = (int)(sv >> 20) >= B;
    unsigned long long m = __ballot(pass);
    if (m) {
      int leader = __ffsll(m) - 1;
      unsigned base = 0;
      if (lane == leader) base = atomicAdd(&cnt[p], (unsigned)__popcll(m));
      base = __shfl(base, leader);
      if (pass) {
        unsigned pos = base + (unsigned)__popcll(m & ((1ULL << lane) - 1ULL));
        if (pos < CAND_CAP) {
          int a = e >> shift;            // e / hw
          int r = e & (hw - 1);          // e % hw
          unsigned kidx = (unsigned)(r * 3 + a);   // reference flatten order (y*W+x)*A + a
          dst[pos] = ((unsigned long long)sv << 32) | (unsigned)(0xFFFFFFFFu - kidx);
        }
      }
    }
  }
}

// ------- exact top-kk per level by rank counting, LDS-staged keys ----------------------
__global__ __launch_bounds__(256) void k_select(const unsigned* cnt, const unsigned long long* ck,
                                                unsigned* selSV, unsigned* selIdx) {
  int p = blockIdx.y; int img = p / 5, lvl = p % 5;
  int Cc = min((int)cnt[p], CAND_CAP);
  if (blockIdx.x * 256 >= Cc) return;
  int kk = (lvl == 4) ? 768 : 1000;
  int soff = lvl * 1000;
  const unsigned long long* keys = ck + (size_t)p * CAND_CAP;
  __shared__ unsigned long long sk[4096];
  int stage = min(Cc, 4096);
  for (int j = threadIdx.x; j < stage; j += 256) sk[j] = keys[j];
  __syncthreads();
  int c = blockIdx.x * 256 + threadIdx.x;
  if (c >= Cc) return;
  unsigned long long kc = keys[c];
  int rank = 0;
#pragma unroll 8
  for (int j = 0; j < stage; ++j) rank += (sk[j] > kc) ? 1 : 0;
  for (int j = stage; j < Cc; ++j) rank += (keys[j] > kc) ? 1 : 0;
  if (rank < kk) {
    int slot = img * K_SEL + soff + rank;
    selSV[slot]  = (unsigned)(kc >> 32);
    selIdx[slot] = 0xFFFFFFFFu - (unsigned)kc;
  }
}

// ---------------- decode + clip + validity for the 4768 selected per image --------------
__global__ __launch_bounds__(256) void k_decode(P5 del, const float* anchors,
                                                const unsigned* selSV, const unsigned* selIdx,
                                                float* boxP, unsigned long long* keyP) {
  int i = blockIdx.x * 256 + threadIdx.x;
  if (i >= K_SEL) return;
  int img = blockIdx.y;
  int lvl = (i < 4000) ? (i / 1000) : 4;
  int f = 256 >> lvl, hw = f * f;
  const int aoffA[5] = {0, 196608, 245760, 258048, 261120};
  int slot = img * K_SEL + i;
  unsigned k = selIdx[slot];
  unsigned sv = selSV[slot];
  int a = (int)(k % 3u); int r = (int)(k / 3u);
  int y = r >> (8 - lvl); int x = r & (f - 1);
  const float* dp = del.p[lvl] + (size_t)(img * 12 + a * 4) * hw + (size_t)y * f + x;
  float d0 = dp[0], d1 = dp[hw], d2 = dp[2 * hw], d3 = dp[3 * hw];
  const float* ar = anchors + (size_t)(aoffA[lvl] + (int)k) * 4;
  float a0 = ar[0], a1 = ar[1], a2 = ar[2], a3 = ar[3];
  // numpy-faithful, no FMA contraction
  float w = __fsub_rn(a2, a0), h = __fsub_rn(a3, a1);
  float cx = __fadd_rn(a0, __fmul_rn(0.5f, w));
  float cy = __fadd_rn(a1, __fmul_rn(0.5f, h));
  const float CLIP = 4.135166556742356f;     // log(1000/16)
  float dw = fminf(d2, CLIP), dh = fminf(d3, CLIP);
  float pcx = __fadd_rn(__fmul_rn(d0, w), cx);
  float pcy = __fadd_rn(__fmul_rn(d1, h), cy);
  float pw = __fmul_rn(expf(dw), w);
  float ph = __fmul_rn(expf(dh), h);
  float x1 = __fsub_rn(pcx, __fmul_rn(0.5f, pw));
  float y1 = __fsub_rn(pcy, __fmul_rn(0.5f, ph));
  float x2 = __fadd_rn(pcx, __fmul_rn(0.5f, pw));
  float y2 = __fadd_rn(pcy, __fmul_rn(0.5f, ph));
  float x1c = fminf(fmaxf(x1, 0.0f), 1024.0f);
  float y1c = fminf(fmaxf(y1, 0.0f), 1024.0f);
  float x2c = fminf(fmaxf(x2, 0.0f), 1024.0f);
  float y2c = fminf(fmaxf(y2, 0.0f), 1024.0f);
  bool valid = (__fsub_rn(x2c, x1c) >= 1e-3f) && (__fsub_rn(y2c, y1c) >= 1e-3f);
  float* bp = boxP + (size_t)slot * 4;
  bp[0] = x1c; bp[1] = y1c; bp[2] = x2c; bp[3] = y2c;
  unsigned low = 0xFFFFFFFFu - (unsigned)i;   // pos asc tie-break, unique keys
  keyP[slot] = valid ? (((unsigned long long)sv << 32) | low) : (unsigned long long)low;
}

// ------- global per-image stable sort by (logit desc, pos asc); emit rank-ordered boxes -
__global__ __launch_bounds__(256) void k_sortrank(const unsigned long long* keyP, const float* boxP,
                                                  float* sBox, int* sMeta) {
  __shared__ unsigned long long lk[K_SEL];
  int img = blockIdx.y;
  for (int t = threadIdx.x; t < K_SEL; t += 256) lk[t] = keyP[(size_t)img * K_SEL + t];
  __syncthreads();
  int i = blockIdx.x * 256 + threadIdx.x;
  if (i >= K_SEL) return;
  unsigned long long ki = lk[i];
  int rank = 0;
#pragma unroll 8
  for (int j = 0; j < K_SEL; ++j) rank += (lk[j] > ki) ? 1 : 0;
  int slot = img * K_SEL + i;
  const float* bp = boxP + (size_t)slot * 4;
  int oslot = img * K_SEL + rank;
  float* op = sBox + (size_t)oslot * 4;
  op[0] = bp[0]; op[1] = bp[1]; op[2] = bp[2]; op[3] = bp[3];
  sMeta[oslot] = (int)(0xFFFFFFFFu - (unsigned)ki);      // original selection pos 0..4767
}

// ---------------- IoU on offset boxes, bitwise matching reference -----------------------
__device__ __forceinline__ bool iou_gt(float rx1, float ry1, float rx2, float ry2, float rar,
                                       float cx1, float cy1, float cx2, float cy2, float car) {
  float ltx = fmaxf(rx1, cx1), lty = fmaxf(ry1, cy1);
  float rbx = fminf(rx2, cx2), rby = fminf(ry2, cy2);
  float wx = fmaxf(__fsub_rn(rbx, ltx), 0.0f);
  float wy = fmaxf(__fsub_rn(rby, lty), 0.0f);
  float inter = __fmul_rn(wx, wy);
  float denom = __fadd_rn(__fsub_rn(__fadd_rn(rar, car), inter), 1e-9f);
  return __fdiv_rn(inter, denom) > 0.7f;
}

// ---- PER-LEVEL upper-triangle suppression bitmask (<=1000 boxes, 16 words/row) ---------
// Suppression is intra-level only (1025*lvl offset => cross-level IoU == 0).
__global__ __launch_bounds__(64) void k_lvlmask(const float* boxP, unsigned long long* gmask) {
  int img = blockIdx.y;
  int q = blockIdx.x;                        // 0..621 per image
  int lvl, q2;
  if (q < 544) { lvl = q / 136; q2 = q - lvl * 136; }
  else         { lvl = 4;       q2 = q - 544; }
  int kk = (lvl == 4) ? 768 : 1000;
  int nch = (kk + 63) >> 6;
  int rb = 0;
  while (q2 >= nch - rb) { q2 -= nch - rb; ++rb; }    // upper-tri (rb, cb>=rb)
  int cb = rb + q2;
  int t = threadIdx.x;
  float off = __fmul_rn((float)lvl, 1025.0f);
  const float4* b4 = (const float4*)boxP + (size_t)img * K_SEL + lvl * 1000;
  __shared__ float cx1[64], cy1[64], cx2[64], cy2[64], car[64];
  int j = cb * 64 + t;
  if (j < kk) {
    float4 bb = b4[j];
    float ox1 = __fadd_rn(bb.x, off), oy1 = __fadd_rn(bb.y, off);
    float ox2 = __fadd_rn(bb.z, off), oy2 = __fadd_rn(bb.w, off);
    cx1[t] = ox1; cy1[t] = oy1; cx2[t] = ox2; cy2[t] = oy2;
    car[t] = __fmul_rn(__fsub_rn(ox2, ox1), __fsub_rn(oy2, oy1));
  }
  __syncthreads();
  int i = rb * 64 + t;
  if (i >= kk) return;
  float4 bb = b4[i];
  float rx1 = __fadd_rn(bb.x, off), ry1 = __fadd_rn(bb.y, off);
  float rx2 = __fadd_rn(bb.z, off), ry2 = __fadd_rn(bb.w, off);
  float rar = __fmul_rn(__fsub_rn(rx2, rx1), __fsub_rn(ry2, ry1));
  unsigned long long bits = 0;
  int jmax = min(64, kk - cb * 64);
  int jj0 = (rb == cb) ? t + 1 : 0;
  for (int jj = jj0; jj < jmax; ++jj) {
    if (iou_gt(rx1, ry1, rx2, ry2, rar, cx1[jj], cy1[jj], cx2[jj], cy2[jj], car[jj]))
      bits |= (1ULL << jj);
  }
  gmask[((size_t)(img * 5 + lvl) * 1000 + i) * 16 + cb] = bits;
}

// ---- per-level greedy NMS: whole mask staged in LDS, single-wave scan, no global trips -
__global__ __launch_bounds__(256) void k_lvlnms(const unsigned long long* keyP,
                                                const unsigned long long* gmask,
                                                unsigned long long* keepw) {
  int p = blockIdx.x; int img = p / 5, lvl = p % 5;
  int kk = (lvl == 4) ? 768 : 1000;
  int nch = (kk + 63) >> 6;
  __shared__ unsigned long long smask[17000];           // 1000 rows x (16+1 pad) words
  __shared__ unsigned char vflag[1000];
  const unsigned long long* gm = gmask + (size_t)p * 1000 * 16;
  int tid = threadIdx.x;
  for (int x = tid; x < kk * 16; x += 256) {            // coalesced global -> padded LDS
    int r = x >> 4, w = x & 15;
    smask[r * 17 + w] = gm[x];
  }
  const unsigned long long* kp = keyP + (size_t)img * K_SEL + lvl * 1000;
  for (int r = tid; r < kk; r += 256) vflag[r] = (kp[r] >> 32) != 0ULL;
  __syncthreads();
  if (tid >= 64) return;                                // single wave scans
  int t = tid;
  unsigned long long remv = 0ULL;                       // lane t owns suppression word t (t<16)
  for (int c = 0; c < nch; ++c) {
    int i = c * 64 + t;
    bool inb = i < kk;
    unsigned long long validm = __ballot(inb && (vflag[inb ? i : 0] != 0));
    unsigned long long wself = inb ? smask[i * 17 + c] : 0ULL;
    unsigned long long cur = __shfl(remv, c);
    unsigned long long candm = validm & ~cur;
    unsigned long long keepm = 0ULL;
    while (candm) {
      int b = __ffsll(candm) - 1;
      keepm |= (1ULL << b);
      candm &= candm - 1;
      candm &= ~__shfl(wself, b);                       // within-chunk suppression
    }
    if (t == 0) keepw[(size_t)p * 16 + c] = keepm;
    if (c + 1 < nch && t < 16) {                        // fold kept rows (LDS only)
      unsigned long long km = keepm;
      while (km) {
        int b0 = __ffsll(km) - 1; km &= km - 1;
        remv |= smask[(c * 64 + b0) * 17 + t];
      }
    }
  }
}

// ---- merge: walk global score order, compact first 1000 kept into d_out ----------------
__global__ __launch_bounds__(64) void k_merge(const float* sBox, const int* sMeta,
                                              const unsigned long long* keepw, float* out) {
  int img = blockIdx.x;
  int t = threadIdx.x;
  __shared__ unsigned long long kw[80];                 // 5 levels x 16 words
  for (int x = t; x < 80; x += 64) kw[x] = keepw[(size_t)img * 80 + x];
  __syncthreads();
  const int* meta = sMeta + (size_t)img * K_SEL;
  const float4* b4 = (const float4*)sBox + (size_t)img * K_SEL;
  float4* out4 = (float4*)out + (size_t)img * 1000;
  int outc = 0;
  for (int c = 0; c < 75 && outc < 1000; ++c) {
    int i = c * 64 + t;
    bool inb = i < K_SEL;
    int pos = meta[inb ? i : 0];
    int lvl = (pos < 4000) ? pos / 1000 : 4;
    int lpos = pos - lvl * 1000;
    bool kept = inb && ((kw[lvl * 16 + (lpos >> 6)] >> (lpos & 63)) & 1ULL);
    unsigned long long keptm = __ballot(kept);
    int idx = outc + (int)__popcll(keptm & ((1ULL << t) - 1ULL));
    if (kept && idx < 1000) out4[idx] = b4[i];
    outc += (int)__popcll(keptm);
  }
  outc = min(outc, 1000);
  for (int s = outc + t; s < 1000; s += 64)
    out4[s] = make_float4(0.f, 0.f, 0.f, 0.f);          // zero-pad tail
}

extern "C" void kernel_launch(void* const* d_in, const int* in_sizes, int n_in,
                              void* d_out, int out_size, void* d_ws, size_t ws_size,
                              hipStream_t stream) {
  (void)in_sizes; (void)n_in;
  // setup_inputs() dict order is INTERLEAVED: obj_l0, delta_l0, obj_l1, delta_l1, ..., anchors
  P5 obj, del;
  for (int i = 0; i < 5; ++i) {
    obj.p[i] = (const float*)d_in[2 * i];
    del.p[i] = (const float*)d_in[2 * i + 1];
  }
  const float* anchors = (const float*)d_in[10];
  float* out = (float*)d_out;
  char* ws = (char*)d_ws;

  // ws layout (bytes)
  unsigned* cnt               = (unsigned*)(ws + 0);                   // 160
  int* Bthr                   = (int*)(ws + 192);                      // 160
  unsigned long long* candK   = (unsigned long long*)(ws + 512);       // 40*16384*8 = 5242880 -> 5243392
  unsigned* selSV             = (unsigned*)(ws + 5243392);             // 152576 -> 5395968
  unsigned* selIdx            = (unsigned*)(ws + 5395968);             // 152576 -> 5548544
  float* boxP                 = (float*)(ws + 5548544);                // 610304 -> 6158848
  unsigned long long* keyP    = (unsigned long long*)(ws + 6158848);   // 305152 -> 6464000
  float* sBox                 = (float*)(ws + 6464000);                // 610304 -> 7074304
  int* sMeta                  = (int*)(ws + 7074304);                  // 152576 -> 7226880
  unsigned long long* keepw   = (unsigned long long*)(ws + 7226880);   // 40*16*8 = 5120 -> 7232000
  unsigned long long* gmask   = (unsigned long long*)(ws + 7232000);   // 40*1000*16*8 = 5120000 -> 12352000
  unsigned* phist             = (unsigned*)(ws + 7232000);             // overlay on gmask (dead before k_lvlmask): 5242880 -> 12474880
  const size_t NEED = 12474880ULL;
  if (ws_size < NEED) { hipMemsetAsync(d_out, 0, (size_t)out_size * 4, stream); return; }

  k_hist    <<<dim3(8, 40), 256, 0, stream>>>(obj, phist);
  k_thresh  <<<40, 256, 0, stream>>>(phist, Bthr, cnt);
  k_gather  <<<dim3(64, 40), 256, 0, stream>>>(obj, Bthr, cnt, candK);
  k_select  <<<dim3(64, 40), 256, 0, stream>>>(cnt, candK, selSV, selIdx);
  k_decode  <<<dim3(19, 8), 256, 0, stream>>>(del, anchors, selSV, selIdx, boxP, keyP);
  k_sortrank<<<dim3(19, 8), 256, 0, stream>>>(keyP, boxP, sBox, sMeta);
  k_lvlmask <<<dim3(622, 8), 64, 0, stream>>>(boxP, gmask);
  k_lvlnms  <<<40, 256, 0, stream>>>(keyP, gmask, keepw);
  k_merge   <<<8, 64, 0, stream>>>(sBox, sMeta, keepw, out);
}

// Round 10
// 479.132 us; speedup vs baseline: 1.7100x; 1.1267x over previous
//
#include <hip/hip_runtime.h>
#include <cstdint>

#define K_SEL 4768
#define CAND_CAP 16384
#define NBIN 4096

struct P5 { const float* p[5]; };

__device__ __forceinline__ unsigned fsortkey(float f) {
  unsigned b = __float_as_uint(f);
  return (b & 0x80000000u) ? ~b : (b | 0x80000000u);
}

// ------- histogram of sortable-logit top-12 bits per (img,lvl): per-block partials ------
__global__ __launch_bounds__(256) void k_hist(P5 obj, unsigned* phist) {
  int p = blockIdx.y; int img = p / 5, lvl = p % 5;
  int f = 256 >> lvl; int n = 3 * f * f;
  __shared__ unsigned lh[NBIN];
  for (int b = threadIdx.x; b < NBIN; b += 256) lh[b] = 0;
  __syncthreads();
  int chunk = (n + gridDim.x - 1) / gridDim.x;
  int e0 = blockIdx.x * chunk, e1 = min(n, e0 + chunk);
  const float* src = obj.p[lvl] + (size_t)img * n;
  for (int e = e0 + threadIdx.x; e < e1; e += 256) {
    unsigned sv = fsortkey(src[e]);
    atomicAdd(&lh[sv >> 20], 1u);
  }
  __syncthreads();
  unsigned* dst = phist + ((size_t)(p * 8 + blockIdx.x)) * NBIN;
  for (int b = threadIdx.x; b < NBIN; b += 256) dst[b] = lh[b];   // unconditional: no pre-zero
}

// ------- sum partials, find threshold bin B (count(bin >= B) >= kk), zero cnt ----------
__global__ __launch_bounds__(256) void k_thresh(const unsigned* phist, int* Bthr, unsigned* cnt) {
  int p = blockIdx.x; int lvl = p % 5;
  unsigned kk = (lvl == 4) ? 768u : 1000u;
  __shared__ unsigned hsum[NBIN];
  __shared__ unsigned csum[256];
  int c = threadIdx.x;
  unsigned tot[16];
#pragma unroll
  for (int k = 0; k < 16; ++k) tot[k] = 0;
  for (int g = 0; g < 8; ++g) {
    const unsigned* hp = phist + ((size_t)(p * 8 + g)) * NBIN + c * 16;
#pragma unroll
    for (int k = 0; k < 16; ++k) tot[k] += hp[k];
  }
  unsigned s = 0;
#pragma unroll
  for (int k = 0; k < 16; ++k) { hsum[c * 16 + k] = tot[k]; s += tot[k]; }
  csum[c] = s;
  __syncthreads();
  if (c == 0) {
    unsigned acc = 0; int B = 0;
    for (int cc = 255; cc >= 0; --cc) {
      if (acc + csum[cc] >= kk) {
        for (int b = 15; b >= 0; --b) {
          acc += hsum[cc * 16 + b];
          if (acc >= kk) { B = cc * 16 + b; break; }
        }
        break;
      }
      acc += csum[cc];
    }
    Bthr[p] = B;
    cnt[p] = 0;                              // replaces ws memset for gather's counter
  }
}

// ------- gather candidates (bin >= B), wave-aggregated atomics, grid-stride ------------
__global__ __launch_bounds__(256) void k_gather(P5 obj, const int* Bthr, unsigned* cnt,
                                                unsigned long long* ck) {
  int p = blockIdx.y; int img = p / 5, lvl = p % 5;
  int f = 256 >> lvl; int hw = f * f; int n = 3 * hw;
  int B = Bthr[p];
  int shift = 2 * (8 - lvl);
  const float* src = obj.p[lvl] + (size_t)img * n;
  unsigned long long* dst = ck + (size_t)p * CAND_CAP;
  int lane = threadIdx.x & 63;
  for (int e = blockIdx.x * 256 + threadIdx.x; e < n; e += gridDim.x * 256) {
    float v = src[e];
    unsigned sv = fsortkey(v);
    bool pass = (int)(sv >> 20) >= B;
    unsigned long long m = __ballot(pass);
    if (m) {
      int leader = __ffsll(m) - 1;
      unsigned base = 0;
      if (lane == leader) base = atomicAdd(&cnt[p], (unsigned)__popcll(m));
      base = __shfl(base, leader);
      if (pass) {
        unsigned pos = base + (unsigned)__popcll(m & ((1ULL << lane) - 1ULL));
        if (pos < CAND_CAP) {
          int a = e >> shift;            // e / hw
          int r = e & (hw - 1);          // e % hw
          unsigned kidx = (unsigned)(r * 3 + a);   // reference flatten order (y*W+x)*A + a
          dst[pos] = ((unsigned long long)sv << 32) | (unsigned)(0xFFFFFFFFu - kidx);
        }
      }
    }
  }
}

// ------- exact top-kk per level by rank counting, LDS-staged keys ----------------------
__global__ __launch_bounds__(256) void k_select(const unsigned* cnt, const unsigned long long* ck,
                                                unsigned* selSV, unsigned* selIdx) {
  int p = blockIdx.y; int img = p / 5, lvl = p % 5;
  int Cc = min((int)cnt[p], CAND_CAP);
  if (blockIdx.x * 256 >= Cc) return;
  int kk = (lvl == 4) ? 768 : 1000;
  int soff = lvl * 1000;
  const unsigned long long* keys = ck + (size_t)p * CAND_CAP;
  __shared__ unsigned long long sk[4096];
  int stage = min(Cc, 4096);
  for (int j = threadIdx.x; j < stage; j += 256) sk[j] = keys[j];
  __syncthreads();
  int c = blockIdx.x * 256 + threadIdx.x;
  if (c >= Cc) return;
  unsigned long long kc = keys[c];
  int rank = 0;
#pragma unroll 8
  for (int j = 0; j < stage; ++j) rank += (sk[j] > kc) ? 1 : 0;
  for (int j = stage; j < Cc; ++j) rank += (keys[j] > kc) ? 1 : 0;
  if (rank < kk) {
    int slot = img * K_SEL + soff + rank;
    selSV[slot]  = (unsigned)(kc >> 32);
    selIdx[slot] = 0xFFFFFFFFu - (unsigned)kc;
  }
}

// ---------------- decode + clip + validity for the 4768 selected per image --------------
__global__ __launch_bounds__(256) void k_decode(P5 del, const float* anchors,
                                                const unsigned* selSV, const unsigned* selIdx,
                                                float* boxP, unsigned long long* keyP) {
  int i = blockIdx.x * 256 + threadIdx.x;
  if (i >= K_SEL) return;
  int img = blockIdx.y;
  int lvl = (i < 4000) ? (i / 1000) : 4;
  int f = 256 >> lvl, hw = f * f;
  const int aoffA[5] = {0, 196608, 245760, 258048, 261120};
  int slot = img * K_SEL + i;
  unsigned k = selIdx[slot];
  unsigned sv = selSV[slot];
  int a = (int)(k % 3u); int r = (int)(k / 3u);
  int y = r >> (8 - lvl); int x = r & (f - 1);
  const float* dp = del.p[lvl] + (size_t)(img * 12 + a * 4) * hw + (size_t)y * f + x;
  float d0 = dp[0], d1 = dp[hw], d2 = dp[2 * hw], d3 = dp[3 * hw];
  const float* ar = anchors + (size_t)(aoffA[lvl] + (int)k) * 4;
  float a0 = ar[0], a1 = ar[1], a2 = ar[2], a3 = ar[3];
  // numpy-faithful, no FMA contraction
  float w = __fsub_rn(a2, a0), h = __fsub_rn(a3, a1);
  float cx = __fadd_rn(a0, __fmul_rn(0.5f, w));
  float cy = __fadd_rn(a1, __fmul_rn(0.5f, h));
  const float CLIP = 4.135166556742356f;     // log(1000/16)
  float dw = fminf(d2, CLIP), dh = fminf(d3, CLIP);
  float pcx = __fadd_rn(__fmul_rn(d0, w), cx);
  float pcy = __fadd_rn(__fmul_rn(d1, h), cy);
  float pw = __fmul_rn(expf(dw), w);
  float ph = __fmul_rn(expf(dh), h);
  float x1 = __fsub_rn(pcx, __fmul_rn(0.5f, pw));
  float y1 = __fsub_rn(pcy, __fmul_rn(0.5f, ph));
  float x2 = __fadd_rn(pcx, __fmul_rn(0.5f, pw));
  float y2 = __fadd_rn(pcy, __fmul_rn(0.5f, ph));
  float x1c = fminf(fmaxf(x1, 0.0f), 1024.0f);
  float y1c = fminf(fmaxf(y1, 0.0f), 1024.0f);
  float x2c = fminf(fmaxf(x2, 0.0f), 1024.0f);
  float y2c = fminf(fmaxf(y2, 0.0f), 1024.0f);
  bool valid = (__fsub_rn(x2c, x1c) >= 1e-3f) && (__fsub_rn(y2c, y1c) >= 1e-3f);
  float* bp = boxP + (size_t)slot * 4;
  bp[0] = x1c; bp[1] = y1c; bp[2] = x2c; bp[3] = y2c;
  unsigned low = 0xFFFFFFFFu - (unsigned)i;   // pos asc tie-break, unique keys
  keyP[slot] = valid ? (((unsigned long long)sv << 32) | low) : (unsigned long long)low;
}

// ------- global per-image stable sort by (logit desc, pos asc); emit rank-ordered boxes -
__global__ __launch_bounds__(256) void k_sortrank(const unsigned long long* keyP, const float* boxP,
                                                  float* sBox, int* sMeta) {
  __shared__ unsigned long long lk[K_SEL];
  int img = blockIdx.y;
  for (int t = threadIdx.x; t < K_SEL; t += 256) lk[t] = keyP[(size_t)img * K_SEL + t];
  __syncthreads();
  int i = blockIdx.x * 256 + threadIdx.x;
  if (i >= K_SEL) return;
  unsigned long long ki = lk[i];
  int rank = 0;
#pragma unroll 8
  for (int j = 0; j < K_SEL; ++j) rank += (lk[j] > ki) ? 1 : 0;
  int slot = img * K_SEL + i;
  const float* bp = boxP + (size_t)slot * 4;
  int oslot = img * K_SEL + rank;
  float* op = sBox + (size_t)oslot * 4;
  op[0] = bp[0]; op[1] = bp[1]; op[2] = bp[2]; op[3] = bp[3];
  sMeta[oslot] = (int)(0xFFFFFFFFu - (unsigned)ki);      // original selection pos 0..4767
}

// ---------------- IoU on offset boxes, bitwise matching reference -----------------------
__device__ __forceinline__ bool iou_gt(float rx1, float ry1, float rx2, float ry2, float rar,
                                       float cx1, float cy1, float cx2, float cy2, float car) {
  float ltx = fmaxf(rx1, cx1), lty = fmaxf(ry1, cy1);
  float rbx = fminf(rx2, cx2), rby = fminf(ry2, cy2);
  float wx = fmaxf(__fsub_rn(rbx, ltx), 0.0f);
  float wy = fmaxf(__fsub_rn(rby, lty), 0.0f);
  float inter = __fmul_rn(wx, wy);
  float denom = __fadd_rn(__fsub_rn(__fadd_rn(rar, car), inter), 1e-9f);
  return __fdiv_rn(inter, denom) > 0.7f;
}

// ---- PER-LEVEL upper-triangle suppression bitmask (<=1000 boxes, 16 words/row) ---------
// Suppression is intra-level only (1025*lvl offset => cross-level IoU == 0).
__global__ __launch_bounds__(64) void k_lvlmask(const float* boxP, unsigned long long* gmask) {
  int img = blockIdx.y;
  int q = blockIdx.x;                        // 0..621 per image
  int lvl, q2;
  if (q < 544) { lvl = q / 136; q2 = q - lvl * 136; }
  else         { lvl = 4;       q2 = q - 544; }
  int kk = (lvl == 4) ? 768 : 1000;
  int nch = (kk + 63) >> 6;
  int rb = 0;
  while (q2 >= nch - rb) { q2 -= nch - rb; ++rb; }    // upper-tri (rb, cb>=rb)
  int cb = rb + q2;
  int t = threadIdx.x;
  float off = __fmul_rn((float)lvl, 1025.0f);
  const float4* b4 = (const float4*)boxP + (size_t)img * K_SEL + lvl * 1000;
  __shared__ float cx1[64], cy1[64], cx2[64], cy2[64], car[64];
  int j = cb * 64 + t;
  if (j < kk) {
    float4 bb = b4[j];
    float ox1 = __fadd_rn(bb.x, off), oy1 = __fadd_rn(bb.y, off);
    float ox2 = __fadd_rn(bb.z, off), oy2 = __fadd_rn(bb.w, off);
    cx1[t] = ox1; cy1[t] = oy1; cx2[t] = ox2; cy2[t] = oy2;
    car[t] = __fmul_rn(__fsub_rn(ox2, ox1), __fsub_rn(oy2, oy1));
  }
  __syncthreads();
  int i = rb * 64 + t;
  if (i >= kk) return;
  float4 bb = b4[i];
  float rx1 = __fadd_rn(bb.x, off), ry1 = __fadd_rn(bb.y, off);
  float rx2 = __fadd_rn(bb.z, off), ry2 = __fadd_rn(bb.w, off);
  float rar = __fmul_rn(__fsub_rn(rx2, rx1), __fsub_rn(ry2, ry1));
  unsigned long long bits = 0;
  int jmax = min(64, kk - cb * 64);
  int jj0 = (rb == cb) ? t + 1 : 0;
  for (int jj = jj0; jj < jmax; ++jj) {
    if (iou_gt(rx1, ry1, rx2, ry2, rar, cx1[jj], cy1[jj], cx2[jj], cy2[jj], car[jj]))
      bits |= (1ULL << jj);
  }
  gmask[((size_t)(img * 5 + lvl) * 1000 + i) * 16 + cb] = bits;
}

// ---- per-level greedy NMS: single wave, remv distributed (group g x word w), ----------
// ---- folds read gmask rows DIRECTLY from global: one 128B line per kept row, ----------
// ---- 16 lanes/row coalesced, 4 rows (groups) + 4-wide batches in flight. --------------
__global__ __launch_bounds__(64) void k_lvlnms(const unsigned long long* keyP,
                                               const unsigned long long* gmask,
                                               unsigned long long* keepw) {
  int p = blockIdx.x; int img = p / 5, lvl = p % 5;
  int kk = (lvl == 4) ? 768 : 1000;
  int nch = (kk + 63) >> 6;
  int t = threadIdx.x;
  int g = t >> 4, w = t & 15;
  const unsigned long long* gm = gmask + (size_t)p * 16000;
  const unsigned long long* kp = keyP + (size_t)img * K_SEL + lvl * 1000;
  unsigned long long rp = 0ULL;              // lane partial: OR over group-g kept rows, word w
  const unsigned long long GMASK4 = 0x1111111111111111ULL;
  int i0 = min(t, kk - 1);
  unsigned long long vpre = kp[i0];                       // prefetch chunk 0
  unsigned long long wpre = gm[(size_t)i0 * 16 + 0];
  for (int c = 0; c < nch; ++c) {
    int i = c * 64 + t;
    bool inb = i < kk;
    unsigned long long validm = __ballot(inb && (vpre >> 32) != 0ULL);
    unsigned long long wself = wpre;
    int cn = (c + 1 < nch) ? c + 1 : c;                   // prefetch next chunk (keep-independent)
    int inx = min(cn * 64 + t, kk - 1);
    vpre = kp[inx];
    wpre = gm[(size_t)inx * 16 + cn];
    unsigned long long cur = __shfl(rp, c) | __shfl(rp, 16 + c) |
                             __shfl(rp, 32 + c) | __shfl(rp, 48 + c);
    unsigned long long candm = validm & ~cur;
    unsigned long long keepm = 0ULL;
    while (candm) {
      int b = __ffsll(candm) - 1;
      keepm |= (1ULL << b);
      candm &= candm - 1;
      candm &= ~__shfl(wself, b);                         // within-chunk suppression
    }
    if (t == 0) keepw[(size_t)p * 16 + c] = keepm;
    if (c + 1 == nch) break;                              // no fold needed after last chunk
    // fold: group g takes kept rows with (row&3)==g (wave-uniform per group -> coalesced
    // 128B line per row); 4-wide batches of independent loads.
    int cbase = c * 64;
    unsigned long long kmg = keepm & (GMASK4 << g);
    while (kmg) {
      int b0 = __ffsll(kmg) - 1; kmg &= kmg - 1;
      int b1 = kmg ? __ffsll(kmg) - 1 : -1; if (b1 >= 0) kmg &= kmg - 1;
      int b2 = kmg ? __ffsll(kmg) - 1 : -1; if (b2 >= 0) kmg &= kmg - 1;
      int b3 = kmg ? __ffsll(kmg) - 1 : -1; if (b3 >= 0) kmg &= kmg - 1;
      unsigned long long v0 = gm[(size_t)(cbase + b0) * 16 + w];
      unsigned long long v1 = (b1 >= 0) ? gm[(size_t)(cbase + b1) * 16 + w] : 0ULL;
      unsigned long long v2 = (b2 >= 0) ? gm[(size_t)(cbase + b2) * 16 + w] : 0ULL;
      unsigned long long v3 = (b3 >= 0) ? gm[(size_t)(cbase + b3) * 16 + w] : 0ULL;
      rp |= (v0 | v1) | (v2 | v3);
    }
    // rows' words w < their chunk are unwritten garbage -> only pollute remv words <= c,
    // which are never read at later chunks (cur reads word c' > c). Harmless.
  }
}

// ---- merge: walk global score order, compact first 1000 kept into d_out ----------------
__global__ __launch_bounds__(64) void k_merge(const float* sBox, const int* sMeta,
                                              const unsigned long long* keepw, float* out) {
  int img = blockIdx.x;
  int t = threadIdx.x;
  __shared__ unsigned long long kw[80];                 // 5 levels x 16 words
  for (int x = t; x < 80; x += 64) kw[x] = keepw[(size_t)img * 80 + x];
  __syncthreads();
  const int* meta = sMeta + (size_t)img * K_SEL;
  const float4* b4 = (const float4*)sBox + (size_t)img * K_SEL;
  float4* out4 = (float4*)out + (size_t)img * 1000;
  int outc = 0;
  int pos = meta[t];                                    // prefetch chunk 0
  for (int c = 0; c < 75 && outc < 1000; ++c) {
    int i = c * 64 + t;
    bool inb = i < K_SEL;
    int mypos = pos;
    int inx = min((c + 1) * 64 + t, K_SEL - 1);
    pos = meta[inx];                                    // prefetch next chunk
    int lvl = (mypos < 4000) ? mypos / 1000 : 4;
    int lpos = mypos - lvl * 1000;
    bool kept = inb && ((kw[lvl * 16 + (lpos >> 6)] >> (lpos & 63)) & 1ULL);
    unsigned long long keptm = __ballot(kept);
    int idx = outc + (int)__popcll(keptm & ((1ULL << t) - 1ULL));
    if (kept && idx < 1000) out4[idx] = b4[i];
    outc += (int)__popcll(keptm);
  }
  outc = min(outc, 1000);
  for (int s = outc + t; s < 1000; s += 64)
    out4[s] = make_float4(0.f, 0.f, 0.f, 0.f);          // zero-pad tail
}

extern "C" void kernel_launch(void* const* d_in, const int* in_sizes, int n_in,
                              void* d_out, int out_size, void* d_ws, size_t ws_size,
                              hipStream_t stream) {
  (void)in_sizes; (void)n_in;
  // setup_inputs() dict order is INTERLEAVED: obj_l0, delta_l0, obj_l1, delta_l1, ..., anchors
  P5 obj, del;
  for (int i = 0; i < 5; ++i) {
    obj.p[i] = (const float*)d_in[2 * i];
    del.p[i] = (const float*)d_in[2 * i + 1];
  }
  const float* anchors = (const float*)d_in[10];
  float* out = (float*)d_out;
  char* ws = (char*)d_ws;

  // ws layout (bytes)
  unsigned* cnt               = (unsigned*)(ws + 0);                   // 160
  int* Bthr                   = (int*)(ws + 192);                      // 160
  unsigned long long* candK   = (unsigned long long*)(ws + 512);       // 40*16384*8 = 5242880 -> 5243392
  unsigned* selSV             = (unsigned*)(ws + 5243392);             // 152576 -> 5395968
  unsigned* selIdx            = (unsigned*)(ws + 5395968);             // 152576 -> 5548544
  float* boxP                 = (float*)(ws + 5548544);                // 610304 -> 6158848
  unsigned long long* keyP    = (unsigned long long*)(ws + 6158848);   // 305152 -> 6464000
  float* sBox                 = (float*)(ws + 6464000);                // 610304 -> 7074304
  int* sMeta                  = (int*)(ws + 7074304);                  // 152576 -> 7226880
  unsigned long long* keepw   = (unsigned long long*)(ws + 7226880);   // 40*16*8 = 5120 -> 7232000
  unsigned long long* gmask   = (unsigned long long*)(ws + 7232000);   // 40*1000*16*8 = 5120000 -> 12352000
  unsigned* phist             = (unsigned*)(ws + 7232000);             // overlay on gmask (dead before k_lvlmask)
  const size_t NEED = 12474880ULL;
  if (ws_size < NEED) { hipMemsetAsync(d_out, 0, (size_t)out_size * 4, stream); return; }

  k_hist    <<<dim3(8, 40), 256, 0, stream>>>(obj, phist);
  k_thresh  <<<40, 256, 0, stream>>>(phist, Bthr, cnt);
  k_gather  <<<dim3(64, 40), 256, 0, stream>>>(obj, Bthr, cnt, candK);
  k_select  <<<dim3(64, 40), 256, 0, stream>>>(cnt, candK, selSV, selIdx);
  k_decode  <<<dim3(19, 8), 256, 0, stream>>>(del, anchors, selSV, selIdx, boxP, keyP);
  k_sortrank<<<dim3(19, 8), 256, 0, stream>>>(keyP, boxP, sBox, sMeta);
  k_lvlmask <<<dim3(622, 8), 64, 0, stream>>>(boxP, gmask);
  k_lvlnms  <<<40, 64, 0, stream>>>(keyP, gmask, keepw);
  k_merge   <<<8, 64, 0, stream>>>(sBox, sMeta, keepw, out);
}

// Round 11
// 398.766 us; speedup vs baseline: 2.0546x; 1.2015x over previous
//
#include <hip/hip_runtime.h>
#include <cstdint>

#define K_SEL 4768
#define CAND_CAP 16384
#define NBIN 4096
#define BUFCAP 512

struct P5 { const float* p[5]; };

__device__ __forceinline__ unsigned fsortkey(float f) {
  unsigned b = __float_as_uint(f);
  return (b & 0x80000000u) ? ~b : (b | 0x80000000u);
}

// ------- histogram of sortable-logit top-12 bits per (img,lvl): per-block partials ------
__global__ __launch_bounds__(256) void k_hist(P5 obj, unsigned* phist) {
  int p = blockIdx.y; int img = p / 5, lvl = p % 5;
  int f = 256 >> lvl; int n = 3 * f * f;
  __shared__ unsigned lh[NBIN];
  for (int b = threadIdx.x; b < NBIN; b += 256) lh[b] = 0;
  __syncthreads();
  int chunk = (n + gridDim.x - 1) / gridDim.x;
  int e0 = blockIdx.x * chunk, e1 = min(n, e0 + chunk);
  const float* src = obj.p[lvl] + (size_t)img * n;
  for (int e = e0 + threadIdx.x; e < e1; e += 256) {
    unsigned sv = fsortkey(src[e]);
    atomicAdd(&lh[sv >> 20], 1u);
  }
  __syncthreads();
  unsigned* dst = phist + ((size_t)(p * 8 + blockIdx.x)) * NBIN;
  for (int b = threadIdx.x; b < NBIN; b += 256) dst[b] = lh[b];   // unconditional: no pre-zero
}

// ------- sum partials, find threshold bin B (count(bin >= B) >= kk), zero cnt ----------
__global__ __launch_bounds__(256) void k_thresh(const unsigned* phist, int* Bthr, unsigned* cnt) {
  int p = blockIdx.x; int lvl = p % 5;
  unsigned kk = (lvl == 4) ? 768u : 1000u;
  __shared__ unsigned hsum[NBIN];
  __shared__ unsigned csum[256];
  int c = threadIdx.x;
  unsigned tot[16];
#pragma unroll
  for (int k = 0; k < 16; ++k) tot[k] = 0;
  for (int g = 0; g < 8; ++g) {
    const unsigned* hp = phist + ((size_t)(p * 8 + g)) * NBIN + c * 16;
#pragma unroll
    for (int k = 0; k < 16; ++k) tot[k] += hp[k];
  }
  unsigned s = 0;
#pragma unroll
  for (int k = 0; k < 16; ++k) { hsum[c * 16 + k] = tot[k]; s += tot[k]; }
  csum[c] = s;
  __syncthreads();
  if (c == 0) {
    unsigned acc = 0; int B = 0;
    for (int cc = 255; cc >= 0; --cc) {
      if (acc + csum[cc] >= kk) {
        for (int b = 15; b >= 0; --b) {
          acc += hsum[cc * 16 + b];
          if (acc >= kk) { B = cc * 16 + b; break; }
        }
        break;
      }
      acc += csum[cc];
    }
    Bthr[p] = B;
    cnt[p] = 0;                              // replaces ws memset for gather's counter
  }
}

// ------- gather candidates (bin >= B): LDS-buffered, ONE atomic per block --------------
__global__ __launch_bounds__(256) void k_gather(P5 obj, const int* Bthr, unsigned* cnt,
                                                unsigned long long* ck) {
  int p = blockIdx.y; int img = p / 5, lvl = p % 5;
  int f = 256 >> lvl; int hw = f * f; int n = 3 * hw;
  int B = Bthr[p];
  int shift = 2 * (8 - lvl);
  const float* src = obj.p[lvl] + (size_t)img * n;
  unsigned long long* dst = ck + (size_t)p * CAND_CAP;
  int tid = threadIdx.x;
  int lane = tid & 63, wv = tid >> 6;
  __shared__ unsigned long long buf[4][BUFCAP];
  __shared__ unsigned wTot[4];
  __shared__ unsigned blkBase;
  unsigned wc = 0;                             // wave-uniform running count
  for (int e = blockIdx.x * 256 + tid; e < n; e += gridDim.x * 256) {
    float v = src[e];
    unsigned sv = fsortkey(v);
    bool pass = (int)(sv >> 20) >= B;
    unsigned long long m = __ballot(pass);
    if (m) {
      if (pass) {
        unsigned pos = wc + (unsigned)__popcll(m & ((1ULL << lane) - 1ULL));
        int a = e >> shift;                    // e / hw
        int r = e & (hw - 1);                  // e % hw
        unsigned kidx = (unsigned)(r * 3 + a); // reference flatten order (y*W+x)*A + a
        unsigned long long key = ((unsigned long long)sv << 32) | (0xFFFFFFFFu - kidx);
        if (pos < BUFCAP) buf[wv][pos] = key;
        else {                                 // overflow safety (pathological skew only)
          unsigned gp = atomicAdd(&cnt[p], 1u);
          if (gp < CAND_CAP) dst[gp] = key;
        }
      }
      wc += (unsigned)__popcll(m);
    }
  }
  if (lane == 0) wTot[wv] = min(wc, (unsigned)BUFCAP);
  __syncthreads();
  if (tid == 0) {
    unsigned tot = wTot[0] + wTot[1] + wTot[2] + wTot[3];
    blkBase = tot ? atomicAdd(&cnt[p], tot) : 0u;
  }
  __syncthreads();
  unsigned myOff = blkBase;
  for (int x = 0; x < wv; ++x) myOff += wTot[x];
  unsigned wn = wTot[wv];
  for (unsigned j = lane; j < wn; j += 64) {
    unsigned gp = myOff + j;
    if (gp < CAND_CAP) dst[gp] = buf[wv][j];   // coalesced flush
  }
}

// ------- exact top-kk per level by rank counting, LDS-staged keys ----------------------
__global__ __launch_bounds__(256) void k_select(const unsigned* cnt, const unsigned long long* ck,
                                                unsigned* selSV, unsigned* selIdx) {
  int p = blockIdx.y; int img = p / 5, lvl = p % 5;
  int Cc = min((int)cnt[p], CAND_CAP);
  if (blockIdx.x * 256 >= Cc) return;
  int kk = (lvl == 4) ? 768 : 1000;
  int soff = lvl * 1000;
  const unsigned long long* keys = ck + (size_t)p * CAND_CAP;
  __shared__ unsigned long long sk[4096];
  int stage = min(Cc, 4096);
  for (int j = threadIdx.x; j < stage; j += 256) sk[j] = keys[j];
  __syncthreads();
  int c = blockIdx.x * 256 + threadIdx.x;
  if (c >= Cc) return;
  unsigned long long kc = keys[c];
  int rank = 0;
#pragma unroll 8
  for (int j = 0; j < stage; ++j) rank += (sk[j] > kc) ? 1 : 0;
  for (int j = stage; j < Cc; ++j) rank += (keys[j] > kc) ? 1 : 0;
  if (rank < kk) {
    int slot = img * K_SEL + soff + rank;
    selSV[slot]  = (unsigned)(kc >> 32);
    selIdx[slot] = 0xFFFFFFFFu - (unsigned)kc;
  }
}

// ---------------- decode + clip + validity for the 4768 selected per image --------------
__global__ __launch_bounds__(256) void k_decode(P5 del, const float* anchors,
                                                const unsigned* selSV, const unsigned* selIdx,
                                                float* boxP, unsigned long long* keyP) {
  int i = blockIdx.x * 256 + threadIdx.x;
  if (i >= K_SEL) return;
  int img = blockIdx.y;
  int lvl = (i < 4000) ? (i / 1000) : 4;
  int f = 256 >> lvl, hw = f * f;
  const int aoffA[5] = {0, 196608, 245760, 258048, 261120};
  int slot = img * K_SEL + i;
  unsigned k = selIdx[slot];
  unsigned sv = selSV[slot];
  int a = (int)(k % 3u); int r = (int)(k / 3u);
  int y = r >> (8 - lvl); int x = r & (f - 1);
  const float* dp = del.p[lvl] + (size_t)(img * 12 + a * 4) * hw + (size_t)y * f + x;
  float d0 = dp[0], d1 = dp[hw], d2 = dp[2 * hw], d3 = dp[3 * hw];
  const float* ar = anchors + (size_t)(aoffA[lvl] + (int)k) * 4;
  float a0 = ar[0], a1 = ar[1], a2 = ar[2], a3 = ar[3];
  // numpy-faithful, no FMA contraction
  float w = __fsub_rn(a2, a0), h = __fsub_rn(a3, a1);
  float cx = __fadd_rn(a0, __fmul_rn(0.5f, w));
  float cy = __fadd_rn(a1, __fmul_rn(0.5f, h));
  const float CLIP = 4.135166556742356f;     // log(1000/16)
  float dw = fminf(d2, CLIP), dh = fminf(d3, CLIP);
  float pcx = __fadd_rn(__fmul_rn(d0, w), cx);
  float pcy = __fadd_rn(__fmul_rn(d1, h), cy);
  float pw = __fmul_rn(expf(dw), w);
  float ph = __fmul_rn(expf(dh), h);
  float x1 = __fsub_rn(pcx, __fmul_rn(0.5f, pw));
  float y1 = __fsub_rn(pcy, __fmul_rn(0.5f, ph));
  float x2 = __fadd_rn(pcx, __fmul_rn(0.5f, pw));
  float y2 = __fadd_rn(pcy, __fmul_rn(0.5f, ph));
  float x1c = fminf(fmaxf(x1, 0.0f), 1024.0f);
  float y1c = fminf(fmaxf(y1, 0.0f), 1024.0f);
  float x2c = fminf(fmaxf(x2, 0.0f), 1024.0f);
  float y2c = fminf(fmaxf(y2, 0.0f), 1024.0f);
  bool valid = (__fsub_rn(x2c, x1c) >= 1e-3f) && (__fsub_rn(y2c, y1c) >= 1e-3f);
  float* bp = boxP + (size_t)slot * 4;
  bp[0] = x1c; bp[1] = y1c; bp[2] = x2c; bp[3] = y2c;
  unsigned low = 0xFFFFFFFFu - (unsigned)i;   // pos asc tie-break, unique keys
  keyP[slot] = valid ? (((unsigned long long)sv << 32) | low) : (unsigned long long)low;
}

// ------- global per-image stable sort by (logit desc, pos asc); emit rank-ordered boxes -
__global__ __launch_bounds__(256) void k_sortrank(const unsigned long long* keyP, const float* boxP,
                                                  float* sBox, int* sMeta) {
  __shared__ unsigned long long lk[K_SEL];
  int img = blockIdx.y;
  for (int t = threadIdx.x; t < K_SEL; t += 256) lk[t] = keyP[(size_t)img * K_SEL + t];
  __syncthreads();
  int i = blockIdx.x * 256 + threadIdx.x;
  if (i >= K_SEL) return;
  unsigned long long ki = lk[i];
  int rank = 0;
#pragma unroll 8
  for (int j = 0; j < K_SEL; ++j) rank += (lk[j] > ki) ? 1 : 0;
  int slot = img * K_SEL + i;
  const float* bp = boxP + (size_t)slot * 4;
  int oslot = img * K_SEL + rank;
  float* op = sBox + (size_t)oslot * 4;
  op[0] = bp[0]; op[1] = bp[1]; op[2] = bp[2]; op[3] = bp[3];
  sMeta[oslot] = (int)(0xFFFFFFFFu - (unsigned)ki);      // original selection pos 0..4767
}

// ---------------- IoU on offset boxes, bitwise matching reference -----------------------
__device__ __forceinline__ bool iou_gt(float rx1, float ry1, float rx2, float ry2, float rar,
                                       float cx1, float cy1, float cx2, float cy2, float car) {
  float ltx = fmaxf(rx1, cx1), lty = fmaxf(ry1, cy1);
  float rbx = fminf(rx2, cx2), rby = fminf(ry2, cy2);
  float wx = fmaxf(__fsub_rn(rbx, ltx), 0.0f);
  float wy = fmaxf(__fsub_rn(rby, lty), 0.0f);
  float inter = __fmul_rn(wx, wy);
  float denom = __fadd_rn(__fsub_rn(__fadd_rn(rar, car), inter), 1e-9f);
  return __fdiv_rn(inter, denom) > 0.7f;
}

// ---- PER-LEVEL upper-triangle suppression bitmask (<=1000 boxes, 16 words/row) ---------
// Suppression is intra-level only (1025*lvl offset => cross-level IoU == 0).
__global__ __launch_bounds__(64) void k_lvlmask(const float* boxP, unsigned long long* gmask) {
  int img = blockIdx.y;
  int q = blockIdx.x;                        // 0..621 per image
  int lvl, q2;
  if (q < 544) { lvl = q / 136; q2 = q - lvl * 136; }
  else         { lvl = 4;       q2 = q - 544; }
  int kk = (lvl == 4) ? 768 : 1000;
  int nch = (kk + 63) >> 6;
  int rb = 0;
  while (q2 >= nch - rb) { q2 -= nch - rb; ++rb; }    // upper-tri (rb, cb>=rb)
  int cb = rb + q2;
  int t = threadIdx.x;
  float off = __fmul_rn((float)lvl, 1025.0f);
  const float4* b4 = (const float4*)boxP + (size_t)img * K_SEL + lvl * 1000;
  __shared__ float cx1[64], cy1[64], cx2[64], cy2[64], car[64];
  int j = cb * 64 + t;
  if (j < kk) {
    float4 bb = b4[j];
    float ox1 = __fadd_rn(bb.x, off), oy1 = __fadd_rn(bb.y, off);
    float ox2 = __fadd_rn(bb.z, off), oy2 = __fadd_rn(bb.w, off);
    cx1[t] = ox1; cy1[t] = oy1; cx2[t] = ox2; cy2[t] = oy2;
    car[t] = __fmul_rn(__fsub_rn(ox2, ox1), __fsub_rn(oy2, oy1));
  }
  __syncthreads();
  int i = rb * 64 + t;
  if (i >= kk) return;
  float4 bb = b4[i];
  float rx1 = __fadd_rn(bb.x, off), ry1 = __fadd_rn(bb.y, off);
  float rx2 = __fadd_rn(bb.z, off), ry2 = __fadd_rn(bb.w, off);
  float rar = __fmul_rn(__fsub_rn(rx2, rx1), __fsub_rn(ry2, ry1));
  unsigned long long bits = 0;
  int jmax = min(64, kk - cb * 64);
  int jj0 = (rb == cb) ? t + 1 : 0;
  for (int jj = jj0; jj < jmax; ++jj) {
    if (iou_gt(rx1, ry1, rx2, ry2, rar, cx1[jj], cy1[jj], cx2[jj], cy2[jj], car[jj]))
      bits |= (1ULL << jj);
  }
  gmask[((size_t)(img * 5 + lvl) * 1000 + i) * 16 + cb] = bits;
}

// ---- per-level greedy NMS: single wave, remv distributed (group g x word w), ----------
// ---- folds read gmask rows DIRECTLY from global: one 128B line per kept row. ----------
__global__ __launch_bounds__(64) void k_lvlnms(const unsigned long long* keyP,
                                               const unsigned long long* gmask,
                                               unsigned long long* keepw) {
  int p = blockIdx.x; int img = p / 5, lvl = p % 5;
  int kk = (lvl == 4) ? 768 : 1000;
  int nch = (kk + 63) >> 6;
  int t = threadIdx.x;
  int g = t >> 4, w = t & 15;
  const unsigned long long* gm = gmask + (size_t)p * 16000;
  const unsigned long long* kp = keyP + (size_t)img * K_SEL + lvl * 1000;
  unsigned long long rp = 0ULL;              // lane partial: OR over group-g kept rows, word w
  const unsigned long long GMASK4 = 0x1111111111111111ULL;
  int i0 = min(t, kk - 1);
  unsigned long long vpre = kp[i0];                       // prefetch chunk 0
  unsigned long long wpre = gm[(size_t)i0 * 16 + 0];
  for (int c = 0; c < nch; ++c) {
    int i = c * 64 + t;
    bool inb = i < kk;
    unsigned long long validm = __ballot(inb && (vpre >> 32) != 0ULL);
    unsigned long long wself = wpre;
    int cn = (c + 1 < nch) ? c + 1 : c;                   // prefetch next chunk (keep-independent)
    int inx = min(cn * 64 + t, kk - 1);
    vpre = kp[inx];
    wpre = gm[(size_t)inx * 16 + cn];
    unsigned long long cur = __shfl(rp, c) | __shfl(rp, 16 + c) |
                             __shfl(rp, 32 + c) | __shfl(rp, 48 + c);
    unsigned long long candm = validm & ~cur;
    unsigned long long keepm = 0ULL;
    while (candm) {
      int b = __ffsll(candm) - 1;
      keepm |= (1ULL << b);
      candm &= candm - 1;
      candm &= ~__shfl(wself, b);                         // within-chunk suppression
    }
    if (t == 0) keepw[(size_t)p * 16 + c] = keepm;
    if (c + 1 == nch) break;                              // no fold needed after last chunk
    int cbase = c * 64;
    unsigned long long kmg = keepm & (GMASK4 << g);
    while (kmg) {
      int b0 = __ffsll(kmg) - 1; kmg &= kmg - 1;
      int b1 = kmg ? __ffsll(kmg) - 1 : -1; if (b1 >= 0) kmg &= kmg - 1;
      int b2 = kmg ? __ffsll(kmg) - 1 : -1; if (b2 >= 0) kmg &= kmg - 1;
      int b3 = kmg ? __ffsll(kmg) - 1 : -1; if (b3 >= 0) kmg &= kmg - 1;
      unsigned long long v0 = gm[(size_t)(cbase + b0) * 16 + w];
      unsigned long long v1 = (b1 >= 0) ? gm[(size_t)(cbase + b1) * 16 + w] : 0ULL;
      unsigned long long v2 = (b2 >= 0) ? gm[(size_t)(cbase + b2) * 16 + w] : 0ULL;
      unsigned long long v3 = (b3 >= 0) ? gm[(size_t)(cbase + b3) * 16 + w] : 0ULL;
      rp |= (v0 | v1) | (v2 | v3);
    }
    // unwritten lower-tri words only pollute remv words <= c, never re-read. Harmless.
  }
}

// ---- merge: walk global score order, compact first 1000 kept into d_out ----------------
__global__ __launch_bounds__(64) void k_merge(const float* sBox, const int* sMeta,
                                              const unsigned long long* keepw, float* out) {
  int img = blockIdx.x;
  int t = threadIdx.x;
  __shared__ unsigned long long kw[80];                 // 5 levels x 16 words
  for (int x = t; x < 80; x += 64) kw[x] = keepw[(size_t)img * 80 + x];
  __syncthreads();
  const int* meta = sMeta + (size_t)img * K_SEL;
  const float4* b4 = (const float4*)sBox + (size_t)img * K_SEL;
  float4* out4 = (float4*)out + (size_t)img * 1000;
  int outc = 0;
  int pos = meta[t];                                    // prefetch chunk 0
  for (int c = 0; c < 75 && outc < 1000; ++c) {
    int i = c * 64 + t;
    bool inb = i < K_SEL;
    int mypos = pos;
    int inx = min((c + 1) * 64 + t, K_SEL - 1);
    pos = meta[inx];                                    // prefetch next chunk
    int lvl = (mypos < 4000) ? mypos / 1000 : 4;
    int lpos = mypos - lvl * 1000;
    bool kept = inb && ((kw[lvl * 16 + (lpos >> 6)] >> (lpos & 63)) & 1ULL);
    unsigned long long keptm = __ballot(kept);
    int idx = outc + (int)__popcll(keptm & ((1ULL << t) - 1ULL));
    if (kept && idx < 1000) out4[idx] = b4[i];
    outc += (int)__popcll(keptm);
  }
  outc = min(outc, 1000);
  for (int s = outc + t; s < 1000; s += 64)
    out4[s] = make_float4(0.f, 0.f, 0.f, 0.f);          // zero-pad tail
}

extern "C" void kernel_launch(void* const* d_in, const int* in_sizes, int n_in,
                              void* d_out, int out_size, void* d_ws, size_t ws_size,
                              hipStream_t stream) {
  (void)in_sizes; (void)n_in;
  // setup_inputs() dict order is INTERLEAVED: obj_l0, delta_l0, obj_l1, delta_l1, ..., anchors
  P5 obj, del;
  for (int i = 0; i < 5; ++i) {
    obj.p[i] = (const float*)d_in[2 * i];
    del.p[i] = (const float*)d_in[2 * i + 1];
  }
  const float* anchors = (const float*)d_in[10];
  float* out = (float*)d_out;
  char* ws = (char*)d_ws;

  // ws layout (bytes)
  unsigned* cnt               = (unsigned*)(ws + 0);                   // 160
  int* Bthr                   = (int*)(ws + 192);                      // 160
  unsigned long long* candK   = (unsigned long long*)(ws + 512);       // 40*16384*8 = 5242880 -> 5243392
  unsigned* selSV             = (unsigned*)(ws + 5243392);             // 152576 -> 5395968
  unsigned* selIdx            = (unsigned*)(ws + 5395968);             // 152576 -> 5548544
  float* boxP                 = (float*)(ws + 5548544);                // 610304 -> 6158848
  unsigned long long* keyP    = (unsigned long long*)(ws + 6158848);   // 305152 -> 6464000
  float* sBox                 = (float*)(ws + 6464000);                // 610304 -> 7074304
  int* sMeta                  = (int*)(ws + 7074304);                  // 152576 -> 7226880
  unsigned long long* keepw   = (unsigned long long*)(ws + 7226880);   // 40*16*8 = 5120 -> 7232000
  unsigned long long* gmask   = (unsigned long long*)(ws + 7232000);   // 40*1000*16*8 = 5120000 -> 12352000
  unsigned* phist             = (unsigned*)(ws + 7232000);             // overlay on gmask (dead before k_lvlmask)
  const size_t NEED = 12474880ULL;
  if (ws_size < NEED) { hipMemsetAsync(d_out, 0, (size_t)out_size * 4, stream); return; }

  k_hist    <<<dim3(8, 40), 256, 0, stream>>>(obj, phist);
  k_thresh  <<<40, 256, 0, stream>>>(phist, Bthr, cnt);
  k_gather  <<<dim3(32, 40), 256, 0, stream>>>(obj, Bthr, cnt, candK);
  k_select  <<<dim3(64, 40), 256, 0, stream>>>(cnt, candK, selSV, selIdx);
  k_decode  <<<dim3(19, 8), 256, 0, stream>>>(del, anchors, selSV, selIdx, boxP, keyP);
  k_sortrank<<<dim3(19, 8), 256, 0, stream>>>(keyP, boxP, sBox, sMeta);
  k_lvlmask <<<dim3(622, 8), 64, 0, stream>>>(boxP, gmask);
  k_lvlnms  <<<40, 64, 0, stream>>>(keyP, gmask, keepw);
  k_merge   <<<8, 64, 0, stream>>>(sBox, sMeta, keepw, out);
}